// Round 4
// baseline (756.854 us; speedup 1.0000x reference)
//
#include <hip/hip_runtime.h>
#include <float.h>

// VQVAE forward, MI355X. Inputs f32, output buffer f32, order [encoded |
// decoded | vq_loss]; harness compares after bf16-rounding both sides.
// KEY (R7 forensics): the np reference computes the VQ distances in FLOAT32
// including the shared ||z||^2 (~0.9) term -> near-ties quantize equal in
// f32 (ULP ~6e-8) and np.argmin tie-breaks FIRST-INDEX. This version
// emulates the np f32 pipeline bit-for-bit: f32 FMA convs (im2col tap order
// ci,ky,kx; bias post-add), numpy pairwise-32 sums, sequential-FMA dot,
// dist=(a+b_k)-2*m_k in f32, first-index argmin, enc = z + (z_q - z) in f32.
//
// R8: conv2vq de-LDS'd (wave-uniform operands -> scalar loads). R9: NHWC
// intermediates for the deconvs (enc_t in the dec-region tail, d1_t in ws).
// R10: split conv2vq -> k_conv2z + k_vq (4 waves/block scan codebook
// quarters, k wave-uniform -> scalar cb loads; ascending-w strict-< combine
// == np first-index; per-block f64 partials). enc/dec passed; LOSS failed:
// k_loss was rewritten for 256 threads but launched with 64 -> 3/4 of the
// partials never summed + uninitialized LDS read.
// R11 (this round): launch k_loss with 256 threads. No other changes.
#pragma clang fp contract(off)
// (explicit fmaf() still emits hardware FMA; everything else stays per-op IEEE)

// numpy pairwise_sum for n=32: r[j]=a[j]; r[j]+=a[8+j]; +=a[16+j]; +=a[24+j];
// result = ((r0+r1)+(r2+r3))+((r4+r5)+(r6+r7))
__device__ __forceinline__ float pw32(const float* p) {
  float r0 = p[0], r1 = p[1], r2 = p[2], r3 = p[3];
  float r4 = p[4], r5 = p[5], r6 = p[6], r7 = p[7];
  r0 += p[8];  r1 += p[9];  r2 += p[10]; r3 += p[11];
  r4 += p[12]; r5 += p[13]; r6 += p[14]; r7 += p[15];
  r0 += p[16]; r1 += p[17]; r2 += p[18]; r3 += p[19];
  r4 += p[20]; r5 += p[21]; r6 += p[22]; r7 += p[23];
  r0 += p[24]; r1 += p[25]; r2 += p[26]; r3 += p[27];
  r4 += p[28]; r5 += p[29]; r6 += p[30]; r7 += p[31];
  return ((r0 + r1) + (r2 + r3)) + ((r4 + r5) + (r6 + r7));
}

// ---- prep: w2t[tap*32+co] = w2[co*256+tap]; bnG[k] = ||c_k||^2 (np pw32) ----
__global__ __launch_bounds__(256) void k_prep(
    const float* __restrict__ w2, const float* __restrict__ cb,
    float* __restrict__ w2t, float* __restrict__ bnG) {
  int t = threadIdx.x;
  for (int i = t; i < 8192; i += 256) {
    int tap = i >> 5, co = i & 31;
    w2t[i] = w2[co * 256 + tap];
  }
  for (int k = t; k < 512; k += 256) {
    float p[32];
    #pragma unroll
    for (int d = 0; d < 32; d++) { float c = cb[k * 32 + d]; p[d] = c * c; }
    bnG[k] = pw32(p);
  }
}

// ---- conv1: f32 FMA, taps (ci,r,c) ascending, bias post-add, relu ----
__global__ __launch_bounds__(256) void k_conv1(
    const float* __restrict__ img, const float* __restrict__ w1,
    const float* __restrict__ b1, float* __restrict__ h1, int b0) {
  __shared__ float w[768]; // (16,3,4,4)
  for (int i = threadIdx.x; i < 768; i += 256) w[i] = w1[i];
  __syncthreads();
  int idx = blockIdx.x * 256 + threadIdx.x;   // bl*2^18 + co*2^14 + y*2^7 + x
  int x  = idx & 127;
  int y  = (idx >> 7) & 127;
  int co = (idx >> 14) & 15;
  int bl = idx >> 18;
  const float* im = img + (long)(b0 + bl) * 196608;
  float a = 0.f;
  int iy0 = 2 * y - 1, ix0 = 2 * x - 1;
  for (int ci = 0; ci < 3; ci++) {
    const float* imc = im + ci * 65536;
    const float* wc  = w + co * 48 + ci * 16;
    for (int r = 0; r < 4; r++) {
      int iy = iy0 + r;
      if ((unsigned)iy >= 256u) continue;     // zero tap: fma(0,w,a)==a exact
      const float* row = imc + iy * 256;
      for (int c = 0; c < 4; c++) {
        int ix = ix0 + c;
        if ((unsigned)ix >= 256u) continue;
        a = fmaf(row[ix], wc[r * 4 + c], a);
      }
    }
  }
  a = a + b1[co];                              // bias added after conv (f32)
  h1[idx] = fmaxf(a, 0.f);
}

// ---- conv2 (f32 FMA) + relu -> z NHWC (enct scratch) ----
// No LDS: w2t / b2 wave-uniform -> scalar loads.
__global__ __launch_bounds__(256, 3) void k_conv2z(
    const float* __restrict__ h1, const float* __restrict__ w2t,
    const float* __restrict__ b2, float* __restrict__ enct, int b0) {
  int t = threadIdx.x;
  int ppix = blockIdx.x * 256 + t;  // bl*4096 + y*64 + x
  int x  = ppix & 63;
  int y  = (ppix >> 6) & 63;
  int bl = ppix >> 12;
  int bg = b0 + bl;

  float z[32];
  #pragma unroll
  for (int q = 0; q < 32; q++) z[q] = 0.f;

  // taps (ci,r,c) ascending, f32 FMA per output channel (order == baseline)
  int iy0 = 2 * y - 1, ix0 = 2 * x - 1;
  for (int ci = 0; ci < 16; ci++) {
    long hbase = (long)bl * 262144 + (long)ci * 16384;
    for (int r = 0; r < 4; r++) {
      int iy = iy0 + r;
      if ((unsigned)iy >= 128u) continue;     // wave-uniform
      const float* hrow = h1 + hbase + (long)iy * 128;
      const float* wrow = w2t + ((ci * 16 + r * 4) << 5);
      for (int c = 0; c < 4; c++) {
        int ix = ix0 + c;
        float hv = ((unsigned)ix < 128u) ? hrow[ix] : 0.f;
        const float* wp = wrow + (c << 5);     // uniform -> s_load_dwordx16 x2
        #pragma unroll
        for (int co = 0; co < 32; co++)
          z[co] = fmaf(hv, wp[co], z[co]);
      }
    }
  }
  float4* et4 = (float4*)(enct + ((long)bg * 4096 + y * 64 + x) * 32);
  #pragma unroll
  for (int d4 = 0; d4 < 8; d4++) {
    float4 v;
    v.x = fmaxf(z[d4 * 4 + 0] + b2[d4 * 4 + 0], 0.f);
    v.y = fmaxf(z[d4 * 4 + 1] + b2[d4 * 4 + 1], 0.f);
    v.z = fmaxf(z[d4 * 4 + 2] + b2[d4 * 4 + 2], 0.f);
    v.w = fmaxf(z[d4 * 4 + 3] + b2[d4 * 4 + 3], 0.f);
    et4[d4] = v;
  }
}

// ---- vq epilogue for channel block W (compile-time -> z stays in regs) ----
template <int W>
__device__ __forceinline__ double vq_epi(const float* cw, const float (&z)[32],
                                         float* __restrict__ enc, long ebase,
                                         float4* et4) {
  double ls = 0.0;
  #pragma unroll
  for (int i4 = 0; i4 < 2; i4++) {
    int d = W * 8 + i4 * 4;
    float f0 = cw[d + 0] - z[d + 0], e0 = z[d + 0] + f0;
    float f1 = cw[d + 1] - z[d + 1], e1 = z[d + 1] + f1;
    float f2 = cw[d + 2] - z[d + 2], e2 = z[d + 2] + f2;
    float f3 = cw[d + 3] - z[d + 3], e3 = z[d + 3] + f3;
    enc[ebase + (long)(d + 0) * 4096] = e0;
    enc[ebase + (long)(d + 1) * 4096] = e1;
    enc[ebase + (long)(d + 2) * 4096] = e2;
    enc[ebase + (long)(d + 3) * 4096] = e3;
    ls += (double)f0 * (double)f0;
    ls += (double)f1 * (double)f1;
    ls += (double)f2 * (double)f2;
    ls += (double)f3 * (double)f3;
    float4 v; v.x = e0; v.y = e1; v.z = e2; v.w = e3;
    et4[W * 2 + i4] = v;                      // in-place final enc_t
  }
  return ls;
}

// ---- vq: block = 4 waves x 64 pixels (one (bl,y) row). Wave w scans codes
// [w*128,(w+1)*128) -- k wave-uniform -> cb/bnG stay SCALAR loads. Per-wave
// argmin -> LDS -> ascending-w strict-< combine == np first-index. z read
// before barrier, enct rewritten in place after barrier (same wave-block).
__global__ __launch_bounds__(256) void k_vq(
    const float* __restrict__ cb, const float* __restrict__ bnG,
    float* __restrict__ enc, float* enct,
    double* __restrict__ partial, int b0) {
  __shared__ float sb[256];
  __shared__ int   sq[256];
  __shared__ double sls[4];
  int t = threadIdx.x, l = t & 63, w = t >> 6;
  int yy = blockIdx.x & 63;                   // blockIdx.x = bl*64 + y
  int bl = blockIdx.x >> 6;
  int bg = b0 + bl;
  long pg = (long)bg * 4096 + yy * 64 + l;    // global pixel (x = lane)

  float z[32];
  const float4* z4 = (const float4*)(enct + pg * 32);
  #pragma unroll
  for (int i = 0; i < 8; i++) {
    float4 v = z4[i];
    z[i * 4 + 0] = v.x; z[i * 4 + 1] = v.y;
    z[i * 4 + 2] = v.z; z[i * 4 + 3] = v.w;
  }
  // a = ||z||^2 via np pairwise-32 of f32 products (redundant per wave, same)
  float pz[32];
  #pragma unroll
  for (int d = 0; d < 32; d++) pz[d] = z[d] * z[d];
  float a = pw32(pz);

  // dist_k = (a + b_k) - 2*m_k, all f32; m_k = sequential FMA dot.
  // 4 k's in flight; per-chain FMA order unchanged; ascending k, strict <.
  int kbase = w << 7;
  float best = FLT_MAX; int bq = kbase;
  for (int k = kbase; k < kbase + 128; k += 4) {
    const float* c0 = cb + (k << 5);          // uniform -> scalar loads
    float m0 = 0.f, m1 = 0.f, m2 = 0.f, m3 = 0.f;
    #pragma unroll
    for (int d = 0; d < 32; d++) {
      m0 = fmaf(z[d], c0[d],      m0);
      m1 = fmaf(z[d], c0[32 + d], m1);
      m2 = fmaf(z[d], c0[64 + d], m2);
      m3 = fmaf(z[d], c0[96 + d], m3);
    }
    float d0 = (a + bnG[k])     - 2.0f * m0;
    float d1 = (a + bnG[k + 1]) - 2.0f * m1;
    float d2 = (a + bnG[k + 2]) - 2.0f * m2;
    float d3 = (a + bnG[k + 3]) - 2.0f * m3;
    if (d0 < best) { best = d0; bq = k; }
    if (d1 < best) { best = d1; bq = k + 1; }
    if (d2 < best) { best = d2; bq = k + 2; }
    if (d3 < best) { best = d3; bq = k + 3; }
  }
  sb[t] = best; sq[t] = bq;
  __syncthreads();
  float gb = sb[l]; int gq = sq[l];
  #pragma unroll
  for (int ww = 1; ww < 4; ww++) {            // ascending k-quarters; ties ->
    float ob = sb[(ww << 6) + l];             // keep lower w (lower k) == np
    int   oq = sq[(ww << 6) + l];
    if (ob < gb) { gb = ob; gq = oq; }
  }

  const float* cw = cb + (gq << 5);           // per-lane gather (L2-hot)
  long ebase = (long)bg * 131072 + yy * 64 + l;
  float4* et4 = (float4*)(enct + pg * 32);
  double ls;
  if      (w == 0) ls = vq_epi<0>(cw, z, enc, ebase, et4);
  else if (w == 1) ls = vq_epi<1>(cw, z, enc, ebase, et4);
  else if (w == 2) ls = vq_epi<2>(cw, z, enc, ebase, et4);
  else             ls = vq_epi<3>(cw, z, enc, ebase, et4);

  #pragma unroll
  for (int off = 32; off > 0; off >>= 1)
    ls += __shfl_down(ls, off, 64);
  if (l == 0) sls[w] = ls;
  __syncthreads();
  if (t == 0)
    partial[(long)b0 * 64 + blockIdx.x] = ((sls[0] + sls[1]) + sls[2]) + sls[3];
}

// ---- deconv1: ConvT(32->16,k4,s2,p1)+relu ----
// Thread = output pixel, acc[16] over all co (16 independent FMA chains).
// Reads enc_t NHWC (float4), writes d1_t NHWC (contiguous 64B per lane).
__global__ __launch_bounds__(256) void k_deconv1(
    const float* __restrict__ enct, const float* __restrict__ dw1,
    const float* __restrict__ db1, float* __restrict__ d1t, int b0) {
  __shared__ float w[8192];
  for (int i = threadIdx.x; i < 8192; i += 256) {
    int co = i & 15, ci = (i >> 4) & 31, kk = i >> 9;
    w[i] = dw1[ci * 256 + co * 16 + kk];
  }
  __syncthreads();
  int idx = blockIdx.x * 256 + threadIdx.x;   // bl*16384 + oy*128 + ox
  int ox = idx & 127;
  int oy = (idx >> 7) & 127;
  int bl = idx >> 14;
  int bg = b0 + bl;
  float acc[16];
  #pragma unroll
  for (int q = 0; q < 16; q++) acc[q] = 0.f;
  int iyt = (oy + 1) >> 1, ixt = (ox + 1) >> 1;
  for (int sy = 0; sy < 2; sy++) {
    int iy = iyt - sy;
    int ky = oy + 1 - 2 * iy;                 // wave-uniform
    if ((unsigned)iy >= 64u || (unsigned)ky >= 4u) continue;
    for (int sx = 0; sx < 2; sx++) {
      int ix = ixt - sx;
      int kx = ox + 1 - 2 * ix;               // per-lane (parity)
      if ((unsigned)ix >= 64u || (unsigned)kx >= 4u) continue;
      const float4* ep4 =
          (const float4*)(enct + ((long)bg * 4096 + iy * 64 + ix) * 32);
      const float4* wl4 = (const float4*)(w + ((ky * 4 + kx) << 9));
      #pragma unroll
      for (int c4 = 0; c4 < 8; c4++) {
        float4 e = ep4[c4];
        #pragma unroll
        for (int j = 0; j < 4; j++) {
          float ev = (j == 0) ? e.x : (j == 1) ? e.y : (j == 2) ? e.z : e.w;
          int ci = c4 * 4 + j;
          #pragma unroll
          for (int q = 0; q < 4; q++) {
            float4 wv = wl4[ci * 4 + q];
            acc[q * 4 + 0] = fmaf(ev, wv.x, acc[q * 4 + 0]);
            acc[q * 4 + 1] = fmaf(ev, wv.y, acc[q * 4 + 1]);
            acc[q * 4 + 2] = fmaf(ev, wv.z, acc[q * 4 + 2]);
            acc[q * 4 + 3] = fmaf(ev, wv.w, acc[q * 4 + 3]);
          }
        }
      }
    }
  }
  float4* o4 = (float4*)(d1t + (long)idx * 16);
  #pragma unroll
  for (int q = 0; q < 4; q++) {
    float4 v;
    v.x = fmaxf(acc[q * 4 + 0] + db1[q * 4 + 0], 0.f);
    v.y = fmaxf(acc[q * 4 + 1] + db1[q * 4 + 1], 0.f);
    v.z = fmaxf(acc[q * 4 + 2] + db1[q * 4 + 2], 0.f);
    v.w = fmaxf(acc[q * 4 + 3] + db1[q * 4 + 3], 0.f);
    o4[q] = v;
  }
}

// ---- deconv2: ConvT(16->3,k4,s2,p1)+relu -> dec f32 ----
// Reads d1_t NHWC: per combo 4x float4 global + 4x b128 LDS + 16 FMA.
__global__ __launch_bounds__(256) void k_deconv2(
    const float* __restrict__ d1t, const float* __restrict__ dw2,
    const float* __restrict__ db2, float* __restrict__ dec, int b0) {
  __shared__ float w[768];
  for (int i = threadIdx.x; i < 768; i += 256) {
    int ci = i & 15, kk = (i >> 4) & 15, co = i >> 8;
    w[i] = dw2[ci * 48 + co * 16 + kk];
  }
  __syncthreads();
  int idx = blockIdx.x * 256 + threadIdx.x;  // (bl*3+co)*65536 + oy*256 + ox
  int ox = idx & 255;
  int oy = (idx >> 8) & 255;
  int bc = idx >> 16;
  int co = bc % 3;
  int bl = bc / 3;
  int bg = b0 + bl;
  float acc = 0.f;
  int iyt = (oy + 1) >> 1, ixt = (ox + 1) >> 1;
  for (int sy = 0; sy < 2; sy++) {
    int iy = iyt - sy;
    int ky = oy + 1 - 2 * iy;
    if ((unsigned)iy >= 128u || (unsigned)ky >= 4u) continue;
    for (int sx = 0; sx < 2; sx++) {
      int ix = ixt - sx;
      int kx = ox + 1 - 2 * ix;
      if ((unsigned)ix >= 128u || (unsigned)kx >= 4u) continue;
      const float4* dp4 =
          (const float4*)(d1t + ((long)bl * 16384 + iy * 128 + ix) * 16);
      const float4* wp4 = (const float4*)(w + ((co * 16 + ky * 4 + kx) << 4));
      #pragma unroll
      for (int c4 = 0; c4 < 4; c4++) {       // ci ascending == before
        float4 dv = dp4[c4];
        float4 wv = wp4[c4];
        acc = fmaf(dv.x, wv.x, acc);
        acc = fmaf(dv.y, wv.y, acc);
        acc = fmaf(dv.z, wv.z, acc);
        acc = fmaf(dv.w, wv.w, acc);
      }
    }
  }
  acc = acc + db2[co];
  dec[(long)(bg * 3 + co) * 65536 + oy * 256 + ox] = fmaxf(acc, 0.f);
}

__global__ __launch_bounds__(256) void k_loss(
    const double* __restrict__ partial, float* __restrict__ out) {
  __shared__ double r[256];
  int t = threadIdx.x;
  double s = 0.0;
  for (int i = t; i < 2048; i += 256) s += partial[i];
  r[t] = s;
  __syncthreads();
  for (int st = 128; st > 0; st >>= 1) {
    if (t < st) r[t] += r[t + st];
    __syncthreads();
  }
  if (t == 0) out[0] = (float)(2.0 * r[0] / 4194304.0);
}

extern "C" void kernel_launch(void* const* d_in, const int* in_sizes, int n_in,
                              void* d_out, int out_size, void* d_ws, size_t ws_size,
                              hipStream_t stream) {
  const float* imgs = (const float*)d_in[0];
  const float* w1   = (const float*)d_in[1];
  const float* b1   = (const float*)d_in[2];
  const float* w2   = (const float*)d_in[3];
  const float* b2   = (const float*)d_in[4];
  const float* cb   = (const float*)d_in[5];
  const float* dw1  = (const float*)d_in[6];
  const float* db1  = (const float*)d_in[7];
  const float* dw2  = (const float*)d_in[8];
  const float* db2  = (const float*)d_in[9];

  float* out = (float*)d_out;
  float* enc = out;               // (32,32,64,64)  f32
  float* dec = out + 4194304;     // (32,3,256,256) f32
  float* vql = out + 10485760;    // scalar         f32
  // enc_t (NHWC scratch, 16 MB) lives at the TAIL of the dec region; for
  // chunk m, dec written so far = m*cc*196608 floats <= 2097152 +
  // m*cc*131072 (enc_t still needed) since m*cc < 32. Stream-serialized.
  float* enct = dec + 2097152;

  // workspace carve (from the top): partial(16K) | bnG(2K) | w2t(32K) | h1/d1t
  long ws = (long)ws_size;
  long top = (ws - 16384) & ~255L;
  double* partial = (double*)((char*)d_ws + top);
  top = (top - 2048) & ~255L;
  float* bnG = (float*)((char*)d_ws + top);
  top = (top - 32768) & ~255L;
  float* w2t = (float*)((char*)d_ws + top);

  k_prep<<<1, 256, 0, stream>>>(w2, cb, w2t, bnG);

  // h1 (encode) and d1_t (decode) alias: each cc MiB, chunked through ws
  int cc = 1;
  for (int c = 32; c >= 1; c >>= 1)
    if ((long)c * 1048576 <= top) { cc = c; break; }

  float* h1 = (float*)d_ws;
  for (int b0 = 0; b0 < 32; b0 += cc) {
    k_conv1<<<cc * 1024, 256, 0, stream>>>(imgs, w1, b1, h1, b0);
    k_conv2z<<<cc * 16, 256, 0, stream>>>(h1, w2t, b2, enct, b0);
    k_vq<<<cc * 64, 256, 0, stream>>>(cb, bnG, enc, enct, partial, b0);
  }

  float* d1t = (float*)d_ws;
  for (int b0 = 0; b0 < 32; b0 += cc) {
    k_deconv1<<<cc * 64, 256, 0, stream>>>(enct, dw1, db1, d1t, b0);
    k_deconv2<<<cc * 768, 256, 0, stream>>>(d1t, dw2, db2, dec, b0);
  }

  k_loss<<<1, 256, 0, stream>>>(partial, vql);
}

// Round 5
// 590.584 us; speedup vs baseline: 1.2815x; 1.2815x over previous
//
#include <hip/hip_runtime.h>
#include <float.h>

// VQVAE forward, MI355X. Inputs f32, output buffer f32, order [encoded |
// decoded | vq_loss]; harness compares after bf16-rounding both sides.
// KEY (R7 forensics): the np reference computes the VQ distances in FLOAT32
// including the shared ||z||^2 (~0.9) term -> near-ties quantize equal in
// f32 (ULP ~6e-8) and np.argmin tie-breaks FIRST-INDEX. This version
// emulates the np f32 pipeline bit-for-bit: f32 FMA convs (im2col tap order
// ci,ky,kx; bias post-add), numpy pairwise-32 sums, sequential-FMA dot,
// dist=(a+b_k)-2*m_k in f32, first-index argmin, enc = z + (z_q - z) in f32.
//
// R8: conv2vq de-LDS'd (wave-uniform operands -> scalar loads). R9: NHWC
// intermediates for the deconvs (enc_t in dec-region tail, d1_t in ws).
// R10/R11: split conv2vq -> k_conv2z + k_vq (4 waves/block, each wave scans
// a codebook quarter). R11 result: k_vq 266us, SGPR_Count 32 -- deriving
// kbase from threadIdx.x>>6 made LLVM's divergence analysis mark k as
// DIVERGENT, so cb/bnG reads became per-lane VMEM broadcasts (latency-bound)
// instead of s_load_dwordx16.
// R12 (this round): force the wave index through readfirstlane -> SGPR ->
// uniform; codebook scan re-scalarizes. Value identical (t>>6 is constant
// across the wave) -> bit-exact. No other changes.
#pragma clang fp contract(off)
// (explicit fmaf() still emits hardware FMA; everything else stays per-op IEEE)

// numpy pairwise_sum for n=32: r[j]=a[j]; r[j]+=a[8+j]; +=a[16+j]; +=a[24+j];
// result = ((r0+r1)+(r2+r3))+((r4+r5)+(r6+r7))
__device__ __forceinline__ float pw32(const float* p) {
  float r0 = p[0], r1 = p[1], r2 = p[2], r3 = p[3];
  float r4 = p[4], r5 = p[5], r6 = p[6], r7 = p[7];
  r0 += p[8];  r1 += p[9];  r2 += p[10]; r3 += p[11];
  r4 += p[12]; r5 += p[13]; r6 += p[14]; r7 += p[15];
  r0 += p[16]; r1 += p[17]; r2 += p[18]; r3 += p[19];
  r4 += p[20]; r5 += p[21]; r6 += p[22]; r7 += p[23];
  r0 += p[24]; r1 += p[25]; r2 += p[26]; r3 += p[27];
  r4 += p[28]; r5 += p[29]; r6 += p[30]; r7 += p[31];
  return ((r0 + r1) + (r2 + r3)) + ((r4 + r5) + (r6 + r7));
}

// ---- prep: w2t[tap*32+co] = w2[co*256+tap]; bnG[k] = ||c_k||^2 (np pw32) ----
__global__ __launch_bounds__(256) void k_prep(
    const float* __restrict__ w2, const float* __restrict__ cb,
    float* __restrict__ w2t, float* __restrict__ bnG) {
  int t = threadIdx.x;
  for (int i = t; i < 8192; i += 256) {
    int tap = i >> 5, co = i & 31;
    w2t[i] = w2[co * 256 + tap];
  }
  for (int k = t; k < 512; k += 256) {
    float p[32];
    #pragma unroll
    for (int d = 0; d < 32; d++) { float c = cb[k * 32 + d]; p[d] = c * c; }
    bnG[k] = pw32(p);
  }
}

// ---- conv1: f32 FMA, taps (ci,r,c) ascending, bias post-add, relu ----
__global__ __launch_bounds__(256) void k_conv1(
    const float* __restrict__ img, const float* __restrict__ w1,
    const float* __restrict__ b1, float* __restrict__ h1, int b0) {
  __shared__ float w[768]; // (16,3,4,4)
  for (int i = threadIdx.x; i < 768; i += 256) w[i] = w1[i];
  __syncthreads();
  int idx = blockIdx.x * 256 + threadIdx.x;   // bl*2^18 + co*2^14 + y*2^7 + x
  int x  = idx & 127;
  int y  = (idx >> 7) & 127;
  int co = (idx >> 14) & 15;
  int bl = idx >> 18;
  const float* im = img + (long)(b0 + bl) * 196608;
  float a = 0.f;
  int iy0 = 2 * y - 1, ix0 = 2 * x - 1;
  for (int ci = 0; ci < 3; ci++) {
    const float* imc = im + ci * 65536;
    const float* wc  = w + co * 48 + ci * 16;
    for (int r = 0; r < 4; r++) {
      int iy = iy0 + r;
      if ((unsigned)iy >= 256u) continue;     // zero tap: fma(0,w,a)==a exact
      const float* row = imc + iy * 256;
      for (int c = 0; c < 4; c++) {
        int ix = ix0 + c;
        if ((unsigned)ix >= 256u) continue;
        a = fmaf(row[ix], wc[r * 4 + c], a);
      }
    }
  }
  a = a + b1[co];                              // bias added after conv (f32)
  h1[idx] = fmaxf(a, 0.f);
}

// ---- conv2 (f32 FMA) + relu -> z NHWC (enct scratch) ----
// No LDS: w2t / b2 wave-uniform -> scalar loads.
__global__ __launch_bounds__(256, 3) void k_conv2z(
    const float* __restrict__ h1, const float* __restrict__ w2t,
    const float* __restrict__ b2, float* __restrict__ enct, int b0) {
  int t = threadIdx.x;
  int ppix = blockIdx.x * 256 + t;  // bl*4096 + y*64 + x
  int x  = ppix & 63;
  int y  = (ppix >> 6) & 63;
  int bl = ppix >> 12;
  int bg = b0 + bl;

  float z[32];
  #pragma unroll
  for (int q = 0; q < 32; q++) z[q] = 0.f;

  // taps (ci,r,c) ascending, f32 FMA per output channel (order == baseline)
  int iy0 = 2 * y - 1, ix0 = 2 * x - 1;
  for (int ci = 0; ci < 16; ci++) {
    long hbase = (long)bl * 262144 + (long)ci * 16384;
    for (int r = 0; r < 4; r++) {
      int iy = iy0 + r;
      if ((unsigned)iy >= 128u) continue;     // wave-uniform
      const float* hrow = h1 + hbase + (long)iy * 128;
      const float* wrow = w2t + ((ci * 16 + r * 4) << 5);
      for (int c = 0; c < 4; c++) {
        int ix = ix0 + c;
        float hv = ((unsigned)ix < 128u) ? hrow[ix] : 0.f;
        const float* wp = wrow + (c << 5);     // uniform -> s_load_dwordx16 x2
        #pragma unroll
        for (int co = 0; co < 32; co++)
          z[co] = fmaf(hv, wp[co], z[co]);
      }
    }
  }
  float4* et4 = (float4*)(enct + ((long)bg * 4096 + y * 64 + x) * 32);
  #pragma unroll
  for (int d4 = 0; d4 < 8; d4++) {
    float4 v;
    v.x = fmaxf(z[d4 * 4 + 0] + b2[d4 * 4 + 0], 0.f);
    v.y = fmaxf(z[d4 * 4 + 1] + b2[d4 * 4 + 1], 0.f);
    v.z = fmaxf(z[d4 * 4 + 2] + b2[d4 * 4 + 2], 0.f);
    v.w = fmaxf(z[d4 * 4 + 3] + b2[d4 * 4 + 3], 0.f);
    et4[d4] = v;
  }
}

// ---- vq epilogue for channel block W (compile-time -> z stays in regs) ----
template <int W>
__device__ __forceinline__ double vq_epi(const float* cw, const float (&z)[32],
                                         float* __restrict__ enc, long ebase,
                                         float4* et4) {
  double ls = 0.0;
  #pragma unroll
  for (int i4 = 0; i4 < 2; i4++) {
    int d = W * 8 + i4 * 4;
    float f0 = cw[d + 0] - z[d + 0], e0 = z[d + 0] + f0;
    float f1 = cw[d + 1] - z[d + 1], e1 = z[d + 1] + f1;
    float f2 = cw[d + 2] - z[d + 2], e2 = z[d + 2] + f2;
    float f3 = cw[d + 3] - z[d + 3], e3 = z[d + 3] + f3;
    enc[ebase + (long)(d + 0) * 4096] = e0;
    enc[ebase + (long)(d + 1) * 4096] = e1;
    enc[ebase + (long)(d + 2) * 4096] = e2;
    enc[ebase + (long)(d + 3) * 4096] = e3;
    ls += (double)f0 * (double)f0;
    ls += (double)f1 * (double)f1;
    ls += (double)f2 * (double)f2;
    ls += (double)f3 * (double)f3;
    float4 v; v.x = e0; v.y = e1; v.z = e2; v.w = e3;
    et4[W * 2 + i4] = v;                      // in-place final enc_t
  }
  return ls;
}

// ---- vq: block = 4 waves x 64 pixels (one (bl,y) row). Wave w scans codes
// [w*128,(w+1)*128). w is pushed through readfirstlane -> SGPR, so k and all
// cb/bnG addresses are compiler-UNIFORM -> s_load_dwordx16 (the R11 regress
// was divergence analysis treating t>>6 as divergent -> VMEM broadcasts).
// Per-wave argmin -> LDS -> ascending-w strict-< combine == np first-index.
__global__ __launch_bounds__(256) void k_vq(
    const float* __restrict__ cb, const float* __restrict__ bnG,
    float* __restrict__ enc, float* enct,
    double* __restrict__ partial, int b0) {
  __shared__ float sb[256];
  __shared__ int   sq[256];
  __shared__ double sls[4];
  int t = threadIdx.x, l = t & 63;
  int w = __builtin_amdgcn_readfirstlane(t >> 6);  // SGPR: uniform by constr.
  int yy = blockIdx.x & 63;                   // blockIdx.x = bl*64 + y
  int bl = blockIdx.x >> 6;
  int bg = b0 + bl;
  long pg = (long)bg * 4096 + yy * 64 + l;    // global pixel (x = lane)

  float z[32];
  const float4* z4 = (const float4*)(enct + pg * 32);
  #pragma unroll
  for (int i = 0; i < 8; i++) {
    float4 v = z4[i];
    z[i * 4 + 0] = v.x; z[i * 4 + 1] = v.y;
    z[i * 4 + 2] = v.z; z[i * 4 + 3] = v.w;
  }
  // a = ||z||^2 via np pairwise-32 of f32 products (redundant per wave, same)
  float pz[32];
  #pragma unroll
  for (int d = 0; d < 32; d++) pz[d] = z[d] * z[d];
  float a = pw32(pz);

  // dist_k = (a + b_k) - 2*m_k, all f32; m_k = sequential FMA dot.
  // 4 k's in flight; per-chain FMA order unchanged; ascending k, strict <.
  int kbase = w << 7;                         // SGPR-uniform
  float best = FLT_MAX; int bq = kbase;
  for (int k = kbase; k < kbase + 128; k += 4) {
    const float* c0 = cb + (k << 5);          // uniform -> scalar loads
    float m0 = 0.f, m1 = 0.f, m2 = 0.f, m3 = 0.f;
    #pragma unroll
    for (int d = 0; d < 32; d++) {
      m0 = fmaf(z[d], c0[d],      m0);
      m1 = fmaf(z[d], c0[32 + d], m1);
      m2 = fmaf(z[d], c0[64 + d], m2);
      m3 = fmaf(z[d], c0[96 + d], m3);
    }
    float d0 = (a + bnG[k])     - 2.0f * m0;
    float d1 = (a + bnG[k + 1]) - 2.0f * m1;
    float d2 = (a + bnG[k + 2]) - 2.0f * m2;
    float d3 = (a + bnG[k + 3]) - 2.0f * m3;
    if (d0 < best) { best = d0; bq = k; }
    if (d1 < best) { best = d1; bq = k + 1; }
    if (d2 < best) { best = d2; bq = k + 2; }
    if (d3 < best) { best = d3; bq = k + 3; }
  }
  sb[t] = best; sq[t] = bq;
  __syncthreads();
  float gb = sb[l]; int gq = sq[l];
  #pragma unroll
  for (int ww = 1; ww < 4; ww++) {            // ascending k-quarters; ties ->
    float ob = sb[(ww << 6) + l];             // keep lower w (lower k) == np
    int   oq = sq[(ww << 6) + l];
    if (ob < gb) { gb = ob; gq = oq; }
  }

  const float* cw = cb + (gq << 5);           // per-lane gather (L2-hot)
  long ebase = (long)bg * 131072 + yy * 64 + l;
  float4* et4 = (float4*)(enct + pg * 32);
  double ls;
  if      (w == 0) ls = vq_epi<0>(cw, z, enc, ebase, et4);
  else if (w == 1) ls = vq_epi<1>(cw, z, enc, ebase, et4);
  else if (w == 2) ls = vq_epi<2>(cw, z, enc, ebase, et4);
  else             ls = vq_epi<3>(cw, z, enc, ebase, et4);

  #pragma unroll
  for (int off = 32; off > 0; off >>= 1)
    ls += __shfl_down(ls, off, 64);
  if (l == 0) sls[w] = ls;
  __syncthreads();
  if (t == 0)
    partial[(long)b0 * 64 + blockIdx.x] = ((sls[0] + sls[1]) + sls[2]) + sls[3];
}

// ---- deconv1: ConvT(32->16,k4,s2,p1)+relu ----
// Thread = output pixel, acc[16] over all co (16 independent FMA chains).
// Reads enc_t NHWC (float4), writes d1_t NHWC (contiguous 64B per lane).
__global__ __launch_bounds__(256) void k_deconv1(
    const float* __restrict__ enct, const float* __restrict__ dw1,
    const float* __restrict__ db1, float* __restrict__ d1t, int b0) {
  __shared__ float w[8192];
  for (int i = threadIdx.x; i < 8192; i += 256) {
    int co = i & 15, ci = (i >> 4) & 31, kk = i >> 9;
    w[i] = dw1[ci * 256 + co * 16 + kk];
  }
  __syncthreads();
  int idx = blockIdx.x * 256 + threadIdx.x;   // bl*16384 + oy*128 + ox
  int ox = idx & 127;
  int oy = (idx >> 7) & 127;
  int bl = idx >> 14;
  int bg = b0 + bl;
  float acc[16];
  #pragma unroll
  for (int q = 0; q < 16; q++) acc[q] = 0.f;
  int iyt = (oy + 1) >> 1, ixt = (ox + 1) >> 1;
  for (int sy = 0; sy < 2; sy++) {
    int iy = iyt - sy;
    int ky = oy + 1 - 2 * iy;                 // wave-uniform
    if ((unsigned)iy >= 64u || (unsigned)ky >= 4u) continue;
    for (int sx = 0; sx < 2; sx++) {
      int ix = ixt - sx;
      int kx = ox + 1 - 2 * ix;               // per-lane (parity)
      if ((unsigned)ix >= 64u || (unsigned)kx >= 4u) continue;
      const float4* ep4 =
          (const float4*)(enct + ((long)bg * 4096 + iy * 64 + ix) * 32);
      const float4* wl4 = (const float4*)(w + ((ky * 4 + kx) << 9));
      #pragma unroll
      for (int c4 = 0; c4 < 8; c4++) {
        float4 e = ep4[c4];
        #pragma unroll
        for (int j = 0; j < 4; j++) {
          float ev = (j == 0) ? e.x : (j == 1) ? e.y : (j == 2) ? e.z : e.w;
          int ci = c4 * 4 + j;
          #pragma unroll
          for (int q = 0; q < 4; q++) {
            float4 wv = wl4[ci * 4 + q];
            acc[q * 4 + 0] = fmaf(ev, wv.x, acc[q * 4 + 0]);
            acc[q * 4 + 1] = fmaf(ev, wv.y, acc[q * 4 + 1]);
            acc[q * 4 + 2] = fmaf(ev, wv.z, acc[q * 4 + 2]);
            acc[q * 4 + 3] = fmaf(ev, wv.w, acc[q * 4 + 3]);
          }
        }
      }
    }
  }
  float4* o4 = (float4*)(d1t + (long)idx * 16);
  #pragma unroll
  for (int q = 0; q < 4; q++) {
    float4 v;
    v.x = fmaxf(acc[q * 4 + 0] + db1[q * 4 + 0], 0.f);
    v.y = fmaxf(acc[q * 4 + 1] + db1[q * 4 + 1], 0.f);
    v.z = fmaxf(acc[q * 4 + 2] + db1[q * 4 + 2], 0.f);
    v.w = fmaxf(acc[q * 4 + 3] + db1[q * 4 + 3], 0.f);
    o4[q] = v;
  }
}

// ---- deconv2: ConvT(16->3,k4,s2,p1)+relu -> dec f32 ----
// Reads d1_t NHWC: per combo 4x float4 global + 4x b128 LDS + 16 FMA.
__global__ __launch_bounds__(256) void k_deconv2(
    const float* __restrict__ d1t, const float* __restrict__ dw2,
    const float* __restrict__ db2, float* __restrict__ dec, int b0) {
  __shared__ float w[768];
  for (int i = threadIdx.x; i < 768; i += 256) {
    int ci = i & 15, kk = (i >> 4) & 15, co = i >> 8;
    w[i] = dw2[ci * 48 + co * 16 + kk];
  }
  __syncthreads();
  int idx = blockIdx.x * 256 + threadIdx.x;  // (bl*3+co)*65536 + oy*256 + ox
  int ox = idx & 255;
  int oy = (idx >> 8) & 255;
  int bc = idx >> 16;
  int co = bc % 3;
  int bl = bc / 3;
  int bg = b0 + bl;
  float acc = 0.f;
  int iyt = (oy + 1) >> 1, ixt = (ox + 1) >> 1;
  for (int sy = 0; sy < 2; sy++) {
    int iy = iyt - sy;
    int ky = oy + 1 - 2 * iy;
    if ((unsigned)iy >= 128u || (unsigned)ky >= 4u) continue;
    for (int sx = 0; sx < 2; sx++) {
      int ix = ixt - sx;
      int kx = ox + 1 - 2 * ix;
      if ((unsigned)ix >= 128u || (unsigned)kx >= 4u) continue;
      const float4* dp4 =
          (const float4*)(d1t + ((long)bl * 16384 + iy * 128 + ix) * 16);
      const float4* wp4 = (const float4*)(w + ((co * 16 + ky * 4 + kx) << 4));
      #pragma unroll
      for (int c4 = 0; c4 < 4; c4++) {       // ci ascending == before
        float4 dv = dp4[c4];
        float4 wv = wp4[c4];
        acc = fmaf(dv.x, wv.x, acc);
        acc = fmaf(dv.y, wv.y, acc);
        acc = fmaf(dv.z, wv.z, acc);
        acc = fmaf(dv.w, wv.w, acc);
      }
    }
  }
  acc = acc + db2[co];
  dec[(long)(bg * 3 + co) * 65536 + oy * 256 + ox] = fmaxf(acc, 0.f);
}

__global__ __launch_bounds__(256) void k_loss(
    const double* __restrict__ partial, float* __restrict__ out) {
  __shared__ double r[256];
  int t = threadIdx.x;
  double s = 0.0;
  for (int i = t; i < 2048; i += 256) s += partial[i];
  r[t] = s;
  __syncthreads();
  for (int st = 128; st > 0; st >>= 1) {
    if (t < st) r[t] += r[t + st];
    __syncthreads();
  }
  if (t == 0) out[0] = (float)(2.0 * r[0] / 4194304.0);
}

extern "C" void kernel_launch(void* const* d_in, const int* in_sizes, int n_in,
                              void* d_out, int out_size, void* d_ws, size_t ws_size,
                              hipStream_t stream) {
  const float* imgs = (const float*)d_in[0];
  const float* w1   = (const float*)d_in[1];
  const float* b1   = (const float*)d_in[2];
  const float* w2   = (const float*)d_in[3];
  const float* b2   = (const float*)d_in[4];
  const float* cb   = (const float*)d_in[5];
  const float* dw1  = (const float*)d_in[6];
  const float* db1  = (const float*)d_in[7];
  const float* dw2  = (const float*)d_in[8];
  const float* db2  = (const float*)d_in[9];

  float* out = (float*)d_out;
  float* enc = out;               // (32,32,64,64)  f32
  float* dec = out + 4194304;     // (32,3,256,256) f32
  float* vql = out + 10485760;    // scalar         f32
  // enc_t (NHWC scratch, 16 MB) lives at the TAIL of the dec region; for
  // chunk m, dec written so far = m*cc*196608 floats <= 2097152 +
  // m*cc*131072 (enc_t still needed) since m*cc < 32. Stream-serialized.
  float* enct = dec + 2097152;

  // workspace carve (from the top): partial(16K) | bnG(2K) | w2t(32K) | h1/d1t
  long ws = (long)ws_size;
  long top = (ws - 16384) & ~255L;
  double* partial = (double*)((char*)d_ws + top);
  top = (top - 2048) & ~255L;
  float* bnG = (float*)((char*)d_ws + top);
  top = (top - 32768) & ~255L;
  float* w2t = (float*)((char*)d_ws + top);

  k_prep<<<1, 256, 0, stream>>>(w2, cb, w2t, bnG);

  // h1 (encode) and d1_t (decode) alias: each cc MiB, chunked through ws
  int cc = 1;
  for (int c = 32; c >= 1; c >>= 1)
    if ((long)c * 1048576 <= top) { cc = c; break; }

  float* h1 = (float*)d_ws;
  for (int b0 = 0; b0 < 32; b0 += cc) {
    k_conv1<<<cc * 1024, 256, 0, stream>>>(imgs, w1, b1, h1, b0);
    k_conv2z<<<cc * 16, 256, 0, stream>>>(h1, w2t, b2, enct, b0);
    k_vq<<<cc * 64, 256, 0, stream>>>(cb, bnG, enc, enct, partial, b0);
  }

  float* d1t = (float*)d_ws;
  for (int b0 = 0; b0 < 32; b0 += cc) {
    k_deconv1<<<cc * 64, 256, 0, stream>>>(enct, dw1, db1, d1t, b0);
    k_deconv2<<<cc * 768, 256, 0, stream>>>(d1t, dw2, db2, dec, b0);
  }

  k_loss<<<1, 256, 0, stream>>>(partial, vql);
}

// Round 6
// 456.963 us; speedup vs baseline: 1.6563x; 1.2924x over previous
//
#include <hip/hip_runtime.h>
#include <float.h>

// VQVAE forward, MI355X. Inputs f32, output buffer f32, order [encoded |
// decoded | vq_loss]; harness compares after bf16-rounding both sides.
// KEY (R7 forensics): the np reference computes the VQ distances in FLOAT32
// including the shared ||z||^2 (~0.9) term -> near-ties quantize equal in
// f32 (ULP ~6e-8) and np.argmin tie-breaks FIRST-INDEX. This version
// emulates the np f32 pipeline bit-for-bit: f32 FMA convs (im2col tap order
// ci,ky,kx; bias post-add), numpy pairwise-32 sums, sequential-FMA dot,
// dist=(a+b_k)-2*m_k in f32, first-index argmin, enc = z + (z_q - z) in f32.
//
// R8: conv2vq de-LDS'd (wave-uniform operands -> scalar loads). R9: NHWC
// intermediates for the deconvs. R10/R11/R12: conv2z + k_vq split; k_vq's
// wave index must go through readfirstlane or divergence analysis turns the
// codebook scan into per-lane VMEM broadcasts (R11: 266us, SGPR=32).
// R13 (this round): k_conv1 was 165-188us at VGPR=16, VALUBusy 21% --
// thread-per-(co,pixel) made one 48-FMA serial chain with a dependent
// scalar load per FMA and 16x redundant image reads. Restructured like
// conv2z: thread = pixel, acc[16] over all co; per tap 1 image load + 16
// FMAs (independent chains); weights pre-transposed w1t[tap][co] -> wave-
// uniform s_load. Per-co chain order (ci,r,c) unchanged; ix handled by
// hv=0 predication (fmaf(+-0,w,a)==a, proven in conv2z) -> bit-exact.
#pragma clang fp contract(off)
// (explicit fmaf() still emits hardware FMA; everything else stays per-op IEEE)

// numpy pairwise_sum for n=32: r[j]=a[j]; r[j]+=a[8+j]; +=a[16+j]; +=a[24+j];
// result = ((r0+r1)+(r2+r3))+((r4+r5)+(r6+r7))
__device__ __forceinline__ float pw32(const float* p) {
  float r0 = p[0], r1 = p[1], r2 = p[2], r3 = p[3];
  float r4 = p[4], r5 = p[5], r6 = p[6], r7 = p[7];
  r0 += p[8];  r1 += p[9];  r2 += p[10]; r3 += p[11];
  r4 += p[12]; r5 += p[13]; r6 += p[14]; r7 += p[15];
  r0 += p[16]; r1 += p[17]; r2 += p[18]; r3 += p[19];
  r4 += p[20]; r5 += p[21]; r6 += p[22]; r7 += p[23];
  r0 += p[24]; r1 += p[25]; r2 += p[26]; r3 += p[27];
  r4 += p[28]; r5 += p[29]; r6 += p[30]; r7 += p[31];
  return ((r0 + r1) + (r2 + r3)) + ((r4 + r5) + (r6 + r7));
}

// ---- prep: w2t[tap*32+co]=w2[co*256+tap]; w1t[tap*16+co]=w1[co*48+tap];
//      bnG[k] = ||c_k||^2 (np pw32) ----
__global__ __launch_bounds__(256) void k_prep(
    const float* __restrict__ w1, const float* __restrict__ w2,
    const float* __restrict__ cb, float* __restrict__ w1t,
    float* __restrict__ w2t, float* __restrict__ bnG) {
  int t = threadIdx.x;
  for (int i = t; i < 8192; i += 256) {
    int tap = i >> 5, co = i & 31;
    w2t[i] = w2[co * 256 + tap];
  }
  for (int i = t; i < 768; i += 256) {
    int tap = i >> 4, co = i & 15;            // tap = ci*16 + r*4 + c
    w1t[i] = w1[co * 48 + tap];
  }
  for (int k = t; k < 512; k += 256) {
    float p[32];
    #pragma unroll
    for (int d = 0; d < 32; d++) { float c = cb[k * 32 + d]; p[d] = c * c; }
    bnG[k] = pw32(p);
  }
}

// ---- conv1: thread = pixel, acc[16] over co; f32 FMA taps (ci,r,c) ----
// Per tap: 1 image load + 16 FMAs with wave-uniform w1t scalar loads.
__global__ __launch_bounds__(256) void k_conv1(
    const float* __restrict__ img, const float* __restrict__ w1t,
    const float* __restrict__ b1, float* __restrict__ h1, int b0) {
  int idx = blockIdx.x * 256 + threadIdx.x;   // bl*16384 + y*128 + x
  int x  = idx & 127;
  int y  = (idx >> 7) & 127;                  // wave-uniform (128 = 2 waves)
  int bl = idx >> 14;
  const float* im = img + (long)(b0 + bl) * 196608;
  float acc[16];
  #pragma unroll
  for (int q = 0; q < 16; q++) acc[q] = 0.f;
  int iy0 = 2 * y - 1, ix0 = 2 * x - 1;
  for (int ci = 0; ci < 3; ci++) {
    const float* imc = im + ci * 65536;
    for (int r = 0; r < 4; r++) {
      int iy = iy0 + r;
      if ((unsigned)iy >= 256u) continue;     // wave-uniform skip (zero row)
      const float* row = imc + iy * 256;
      for (int c = 0; c < 4; c++) {
        int ix = ix0 + c;
        float hv = ((unsigned)ix < 256u) ? row[ix] : 0.f;  // fmaf(0,w,a)==a
        const float* wp = w1t + ((ci * 16 + r * 4 + c) << 4);  // uniform
        #pragma unroll
        for (int co = 0; co < 16; co++)
          acc[co] = fmaf(hv, wp[co], acc[co]);
      }
    }
  }
  long hbase = (long)bl * 262144 + y * 128 + x;
  #pragma unroll
  for (int co = 0; co < 16; co++)             // bias post-add, relu
    h1[hbase + (long)co * 16384] = fmaxf(acc[co] + b1[co], 0.f);
}

// ---- conv2 (f32 FMA) + relu -> z NHWC (enct scratch) ----
// No LDS: w2t / b2 wave-uniform -> scalar loads.
__global__ __launch_bounds__(256, 3) void k_conv2z(
    const float* __restrict__ h1, const float* __restrict__ w2t,
    const float* __restrict__ b2, float* __restrict__ enct, int b0) {
  int t = threadIdx.x;
  int ppix = blockIdx.x * 256 + t;  // bl*4096 + y*64 + x
  int x  = ppix & 63;
  int y  = (ppix >> 6) & 63;
  int bl = ppix >> 12;
  int bg = b0 + bl;

  float z[32];
  #pragma unroll
  for (int q = 0; q < 32; q++) z[q] = 0.f;

  // taps (ci,r,c) ascending, f32 FMA per output channel (order == baseline)
  int iy0 = 2 * y - 1, ix0 = 2 * x - 1;
  for (int ci = 0; ci < 16; ci++) {
    long hbase = (long)bl * 262144 + (long)ci * 16384;
    for (int r = 0; r < 4; r++) {
      int iy = iy0 + r;
      if ((unsigned)iy >= 128u) continue;     // wave-uniform
      const float* hrow = h1 + hbase + (long)iy * 128;
      const float* wrow = w2t + ((ci * 16 + r * 4) << 5);
      for (int c = 0; c < 4; c++) {
        int ix = ix0 + c;
        float hv = ((unsigned)ix < 128u) ? hrow[ix] : 0.f;
        const float* wp = wrow + (c << 5);     // uniform -> s_load_dwordx16 x2
        #pragma unroll
        for (int co = 0; co < 32; co++)
          z[co] = fmaf(hv, wp[co], z[co]);
      }
    }
  }
  float4* et4 = (float4*)(enct + ((long)bg * 4096 + y * 64 + x) * 32);
  #pragma unroll
  for (int d4 = 0; d4 < 8; d4++) {
    float4 v;
    v.x = fmaxf(z[d4 * 4 + 0] + b2[d4 * 4 + 0], 0.f);
    v.y = fmaxf(z[d4 * 4 + 1] + b2[d4 * 4 + 1], 0.f);
    v.z = fmaxf(z[d4 * 4 + 2] + b2[d4 * 4 + 2], 0.f);
    v.w = fmaxf(z[d4 * 4 + 3] + b2[d4 * 4 + 3], 0.f);
    et4[d4] = v;
  }
}

// ---- vq epilogue for channel block W (compile-time -> z stays in regs) ----
template <int W>
__device__ __forceinline__ double vq_epi(const float* cw, const float (&z)[32],
                                         float* __restrict__ enc, long ebase,
                                         float4* et4) {
  double ls = 0.0;
  #pragma unroll
  for (int i4 = 0; i4 < 2; i4++) {
    int d = W * 8 + i4 * 4;
    float f0 = cw[d + 0] - z[d + 0], e0 = z[d + 0] + f0;
    float f1 = cw[d + 1] - z[d + 1], e1 = z[d + 1] + f1;
    float f2 = cw[d + 2] - z[d + 2], e2 = z[d + 2] + f2;
    float f3 = cw[d + 3] - z[d + 3], e3 = z[d + 3] + f3;
    enc[ebase + (long)(d + 0) * 4096] = e0;
    enc[ebase + (long)(d + 1) * 4096] = e1;
    enc[ebase + (long)(d + 2) * 4096] = e2;
    enc[ebase + (long)(d + 3) * 4096] = e3;
    ls += (double)f0 * (double)f0;
    ls += (double)f1 * (double)f1;
    ls += (double)f2 * (double)f2;
    ls += (double)f3 * (double)f3;
    float4 v; v.x = e0; v.y = e1; v.z = e2; v.w = e3;
    et4[W * 2 + i4] = v;                      // in-place final enc_t
  }
  return ls;
}

// ---- vq: block = 4 waves x 64 pixels (one (bl,y) row). Wave w scans codes
// [w*128,(w+1)*128). w is pushed through readfirstlane -> SGPR, so k and all
// cb/bnG addresses are compiler-UNIFORM -> s_load_dwordx16 (the R11 regress
// was divergence analysis treating t>>6 as divergent -> VMEM broadcasts).
// Per-wave argmin -> LDS -> ascending-w strict-< combine == np first-index.
__global__ __launch_bounds__(256) void k_vq(
    const float* __restrict__ cb, const float* __restrict__ bnG,
    float* __restrict__ enc, float* enct,
    double* __restrict__ partial, int b0) {
  __shared__ float sb[256];
  __shared__ int   sq[256];
  __shared__ double sls[4];
  int t = threadIdx.x, l = t & 63;
  int w = __builtin_amdgcn_readfirstlane(t >> 6);  // SGPR: uniform by constr.
  int yy = blockIdx.x & 63;                   // blockIdx.x = bl*64 + y
  int bl = blockIdx.x >> 6;
  int bg = b0 + bl;
  long pg = (long)bg * 4096 + yy * 64 + l;    // global pixel (x = lane)

  float z[32];
  const float4* z4 = (const float4*)(enct + pg * 32);
  #pragma unroll
  for (int i = 0; i < 8; i++) {
    float4 v = z4[i];
    z[i * 4 + 0] = v.x; z[i * 4 + 1] = v.y;
    z[i * 4 + 2] = v.z; z[i * 4 + 3] = v.w;
  }
  // a = ||z||^2 via np pairwise-32 of f32 products (redundant per wave, same)
  float pz[32];
  #pragma unroll
  for (int d = 0; d < 32; d++) pz[d] = z[d] * z[d];
  float a = pw32(pz);

  // dist_k = (a + b_k) - 2*m_k, all f32; m_k = sequential FMA dot.
  // 4 k's in flight; per-chain FMA order unchanged; ascending k, strict <.
  int kbase = w << 7;                         // SGPR-uniform
  float best = FLT_MAX; int bq = kbase;
  for (int k = kbase; k < kbase + 128; k += 4) {
    const float* c0 = cb + (k << 5);          // uniform -> scalar loads
    float m0 = 0.f, m1 = 0.f, m2 = 0.f, m3 = 0.f;
    #pragma unroll
    for (int d = 0; d < 32; d++) {
      m0 = fmaf(z[d], c0[d],      m0);
      m1 = fmaf(z[d], c0[32 + d], m1);
      m2 = fmaf(z[d], c0[64 + d], m2);
      m3 = fmaf(z[d], c0[96 + d], m3);
    }
    float d0 = (a + bnG[k])     - 2.0f * m0;
    float d1 = (a + bnG[k + 1]) - 2.0f * m1;
    float d2 = (a + bnG[k + 2]) - 2.0f * m2;
    float d3 = (a + bnG[k + 3]) - 2.0f * m3;
    if (d0 < best) { best = d0; bq = k; }
    if (d1 < best) { best = d1; bq = k + 1; }
    if (d2 < best) { best = d2; bq = k + 2; }
    if (d3 < best) { best = d3; bq = k + 3; }
  }
  sb[t] = best; sq[t] = bq;
  __syncthreads();
  float gb = sb[l]; int gq = sq[l];
  #pragma unroll
  for (int ww = 1; ww < 4; ww++) {            // ascending k-quarters; ties ->
    float ob = sb[(ww << 6) + l];             // keep lower w (lower k) == np
    int   oq = sq[(ww << 6) + l];
    if (ob < gb) { gb = ob; gq = oq; }
  }

  const float* cw = cb + (gq << 5);           // per-lane gather (L2-hot)
  long ebase = (long)bg * 131072 + yy * 64 + l;
  float4* et4 = (float4*)(enct + pg * 32);
  double ls;
  if      (w == 0) ls = vq_epi<0>(cw, z, enc, ebase, et4);
  else if (w == 1) ls = vq_epi<1>(cw, z, enc, ebase, et4);
  else if (w == 2) ls = vq_epi<2>(cw, z, enc, ebase, et4);
  else             ls = vq_epi<3>(cw, z, enc, ebase, et4);

  #pragma unroll
  for (int off = 32; off > 0; off >>= 1)
    ls += __shfl_down(ls, off, 64);
  if (l == 0) sls[w] = ls;
  __syncthreads();
  if (t == 0)
    partial[(long)b0 * 64 + blockIdx.x] = ((sls[0] + sls[1]) + sls[2]) + sls[3];
}

// ---- deconv1: ConvT(32->16,k4,s2,p1)+relu ----
// Thread = output pixel, acc[16] over all co (16 independent FMA chains).
// Reads enc_t NHWC (float4), writes d1_t NHWC (contiguous 64B per lane).
__global__ __launch_bounds__(256) void k_deconv1(
    const float* __restrict__ enct, const float* __restrict__ dw1,
    const float* __restrict__ db1, float* __restrict__ d1t, int b0) {
  __shared__ float w[8192];
  for (int i = threadIdx.x; i < 8192; i += 256) {
    int co = i & 15, ci = (i >> 4) & 31, kk = i >> 9;
    w[i] = dw1[ci * 256 + co * 16 + kk];
  }
  __syncthreads();
  int idx = blockIdx.x * 256 + threadIdx.x;   // bl*16384 + oy*128 + ox
  int ox = idx & 127;
  int oy = (idx >> 7) & 127;
  int bl = idx >> 14;
  int bg = b0 + bl;
  float acc[16];
  #pragma unroll
  for (int q = 0; q < 16; q++) acc[q] = 0.f;
  int iyt = (oy + 1) >> 1, ixt = (ox + 1) >> 1;
  for (int sy = 0; sy < 2; sy++) {
    int iy = iyt - sy;
    int ky = oy + 1 - 2 * iy;                 // wave-uniform
    if ((unsigned)iy >= 64u || (unsigned)ky >= 4u) continue;
    for (int sx = 0; sx < 2; sx++) {
      int ix = ixt - sx;
      int kx = ox + 1 - 2 * ix;               // per-lane (parity)
      if ((unsigned)ix >= 64u || (unsigned)kx >= 4u) continue;
      const float4* ep4 =
          (const float4*)(enct + ((long)bg * 4096 + iy * 64 + ix) * 32);
      const float4* wl4 = (const float4*)(w + ((ky * 4 + kx) << 9));
      #pragma unroll
      for (int c4 = 0; c4 < 8; c4++) {
        float4 e = ep4[c4];
        #pragma unroll
        for (int j = 0; j < 4; j++) {
          float ev = (j == 0) ? e.x : (j == 1) ? e.y : (j == 2) ? e.z : e.w;
          int ci = c4 * 4 + j;
          #pragma unroll
          for (int q = 0; q < 4; q++) {
            float4 wv = wl4[ci * 4 + q];
            acc[q * 4 + 0] = fmaf(ev, wv.x, acc[q * 4 + 0]);
            acc[q * 4 + 1] = fmaf(ev, wv.y, acc[q * 4 + 1]);
            acc[q * 4 + 2] = fmaf(ev, wv.z, acc[q * 4 + 2]);
            acc[q * 4 + 3] = fmaf(ev, wv.w, acc[q * 4 + 3]);
          }
        }
      }
    }
  }
  float4* o4 = (float4*)(d1t + (long)idx * 16);
  #pragma unroll
  for (int q = 0; q < 4; q++) {
    float4 v;
    v.x = fmaxf(acc[q * 4 + 0] + db1[q * 4 + 0], 0.f);
    v.y = fmaxf(acc[q * 4 + 1] + db1[q * 4 + 1], 0.f);
    v.z = fmaxf(acc[q * 4 + 2] + db1[q * 4 + 2], 0.f);
    v.w = fmaxf(acc[q * 4 + 3] + db1[q * 4 + 3], 0.f);
    o4[q] = v;
  }
}

// ---- deconv2: ConvT(16->3,k4,s2,p1)+relu -> dec f32 ----
// Reads d1_t NHWC: per combo 4x float4 global + 4x b128 LDS + 16 FMA.
__global__ __launch_bounds__(256) void k_deconv2(
    const float* __restrict__ d1t, const float* __restrict__ dw2,
    const float* __restrict__ db2, float* __restrict__ dec, int b0) {
  __shared__ float w[768];
  for (int i = threadIdx.x; i < 768; i += 256) {
    int ci = i & 15, kk = (i >> 4) & 15, co = i >> 8;
    w[i] = dw2[ci * 48 + co * 16 + kk];
  }
  __syncthreads();
  int idx = blockIdx.x * 256 + threadIdx.x;  // (bl*3+co)*65536 + oy*256 + ox
  int ox = idx & 255;
  int oy = (idx >> 8) & 255;
  int bc = idx >> 16;
  int co = bc % 3;
  int bl = bc / 3;
  int bg = b0 + bl;
  float acc = 0.f;
  int iyt = (oy + 1) >> 1, ixt = (ox + 1) >> 1;
  for (int sy = 0; sy < 2; sy++) {
    int iy = iyt - sy;
    int ky = oy + 1 - 2 * iy;
    if ((unsigned)iy >= 128u || (unsigned)ky >= 4u) continue;
    for (int sx = 0; sx < 2; sx++) {
      int ix = ixt - sx;
      int kx = ox + 1 - 2 * ix;
      if ((unsigned)ix >= 128u || (unsigned)kx >= 4u) continue;
      const float4* dp4 =
          (const float4*)(d1t + ((long)bl * 16384 + iy * 128 + ix) * 16);
      const float4* wp4 = (const float4*)(w + ((co * 16 + ky * 4 + kx) << 4));
      #pragma unroll
      for (int c4 = 0; c4 < 4; c4++) {       // ci ascending == before
        float4 dv = dp4[c4];
        float4 wv = wp4[c4];
        acc = fmaf(dv.x, wv.x, acc);
        acc = fmaf(dv.y, wv.y, acc);
        acc = fmaf(dv.z, wv.z, acc);
        acc = fmaf(dv.w, wv.w, acc);
      }
    }
  }
  acc = acc + db2[co];
  dec[(long)(bg * 3 + co) * 65536 + oy * 256 + ox] = fmaxf(acc, 0.f);
}

__global__ __launch_bounds__(256) void k_loss(
    const double* __restrict__ partial, float* __restrict__ out) {
  __shared__ double r[256];
  int t = threadIdx.x;
  double s = 0.0;
  for (int i = t; i < 2048; i += 256) s += partial[i];
  r[t] = s;
  __syncthreads();
  for (int st = 128; st > 0; st >>= 1) {
    if (t < st) r[t] += r[t + st];
    __syncthreads();
  }
  if (t == 0) out[0] = (float)(2.0 * r[0] / 4194304.0);
}

extern "C" void kernel_launch(void* const* d_in, const int* in_sizes, int n_in,
                              void* d_out, int out_size, void* d_ws, size_t ws_size,
                              hipStream_t stream) {
  const float* imgs = (const float*)d_in[0];
  const float* w1   = (const float*)d_in[1];
  const float* b1   = (const float*)d_in[2];
  const float* w2   = (const float*)d_in[3];
  const float* b2   = (const float*)d_in[4];
  const float* cb   = (const float*)d_in[5];
  const float* dw1  = (const float*)d_in[6];
  const float* db1  = (const float*)d_in[7];
  const float* dw2  = (const float*)d_in[8];
  const float* db2  = (const float*)d_in[9];

  float* out = (float*)d_out;
  float* enc = out;               // (32,32,64,64)  f32
  float* dec = out + 4194304;     // (32,3,256,256) f32
  float* vql = out + 10485760;    // scalar         f32
  // enc_t (NHWC scratch, 16 MB) lives at the TAIL of the dec region; for
  // chunk m, dec written so far = m*cc*196608 floats <= 2097152 +
  // m*cc*131072 (enc_t still needed) since m*cc < 32. Stream-serialized.
  float* enct = dec + 2097152;

  // ws carve (top): partial(16K) | bnG(2K) | w2t(32K) | w1t(3K) | h1/d1t below
  long ws = (long)ws_size;
  long top = (ws - 16384) & ~255L;
  double* partial = (double*)((char*)d_ws + top);
  top = (top - 2048) & ~255L;
  float* bnG = (float*)((char*)d_ws + top);
  top = (top - 32768) & ~255L;
  float* w2t = (float*)((char*)d_ws + top);
  top = (top - 3072) & ~255L;
  float* w1t = (float*)((char*)d_ws + top);

  k_prep<<<1, 256, 0, stream>>>(w1, w2, cb, w1t, w2t, bnG);

  // h1 (encode) and d1_t (decode) alias: each cc MiB, chunked through ws
  int cc = 1;
  for (int c = 32; c >= 1; c >>= 1)
    if ((long)c * 1048576 <= top) { cc = c; break; }

  float* h1 = (float*)d_ws;
  for (int b0 = 0; b0 < 32; b0 += cc) {
    k_conv1<<<cc * 64, 256, 0, stream>>>(imgs, w1t, b1, h1, b0);
    k_conv2z<<<cc * 16, 256, 0, stream>>>(h1, w2t, b2, enct, b0);
    k_vq<<<cc * 64, 256, 0, stream>>>(cb, bnG, enc, enct, partial, b0);
  }

  float* d1t = (float*)d_ws;
  for (int b0 = 0; b0 < 32; b0 += cc) {
    k_deconv1<<<cc * 64, 256, 0, stream>>>(enct, dw1, db1, d1t, b0);
    k_deconv2<<<cc * 768, 256, 0, stream>>>(d1t, dw2, db2, dec, b0);
  }

  k_loss<<<1, 256, 0, stream>>>(partial, vql);
}

// Round 8
// 385.621 us; speedup vs baseline: 1.9627x; 1.1850x over previous
//
#include <hip/hip_runtime.h>
#include <float.h>

// VQVAE forward, MI355X. Inputs f32, output buffer f32, order [encoded |
// decoded | vq_loss]; harness compares after bf16-rounding both sides.
// KEY (R7 forensics): the np reference computes the VQ distances in FLOAT32
// including the shared ||z||^2 (~0.9) term -> near-ties quantize equal in
// f32 (ULP ~6e-8) and np.argmin tie-breaks FIRST-INDEX. This version
// emulates the np f32 pipeline bit-for-bit: f32 FMA convs (im2col tap order
// ci,ky,kx; bias post-add), numpy pairwise-32 sums, sequential-FMA dot,
// dist=(a+b_k)-2*m_k in f32, first-index argmin, enc = z + (z_q - z) in f32.
//
// R8: conv2vq de-LDS'd (wave-uniform operands -> scalar loads). R9: NHWC
// intermediates for the deconvs. R10-R12: conv2z + k_vq split (wave index
// through readfirstlane to keep the codebook scan scalar). R13: conv1
// restructured thread=pixel/acc[16] (was a 48-FMA serial chain at VGPR=16).
// R14: k_deconv2 was 125us with FETCH 65.3MB vs 32MB ideal --
// thread-per-(co,pixel) made the 3 co-threads re-read identical d1t
// vectors (3x redundant global loads + 3x addr calc). Now thread = output
// pixel, acc[3] over co: d1t float4s loaded ONCE per tap-combo, co loop
// reuses them from registers. Per-co FMA chain order ((sy,sx) outer, ci
// ascending) unchanged -> bit-exact. 3 coalesced plane stores.
// R15 (this round): R14 never ran (container infra failure twice) --
// resubmitting R14 unchanged for a clean measurement.
#pragma clang fp contract(off)
// (explicit fmaf() still emits hardware FMA; everything else stays per-op IEEE)

// numpy pairwise_sum for n=32: r[j]=a[j]; r[j]+=a[8+j]; +=a[16+j]; +=a[24+j];
// result = ((r0+r1)+(r2+r3))+((r4+r5)+(r6+r7))
__device__ __forceinline__ float pw32(const float* p) {
  float r0 = p[0], r1 = p[1], r2 = p[2], r3 = p[3];
  float r4 = p[4], r5 = p[5], r6 = p[6], r7 = p[7];
  r0 += p[8];  r1 += p[9];  r2 += p[10]; r3 += p[11];
  r4 += p[12]; r5 += p[13]; r6 += p[14]; r7 += p[15];
  r0 += p[16]; r1 += p[17]; r2 += p[18]; r3 += p[19];
  r4 += p[20]; r5 += p[21]; r6 += p[22]; r7 += p[23];
  r0 += p[24]; r1 += p[25]; r2 += p[26]; r3 += p[27];
  r4 += p[28]; r5 += p[29]; r6 += p[30]; r7 += p[31];
  return ((r0 + r1) + (r2 + r3)) + ((r4 + r5) + (r6 + r7));
}

// ---- prep: w2t[tap*32+co]=w2[co*256+tap]; w1t[tap*16+co]=w1[co*48+tap];
//      bnG[k] = ||c_k||^2 (np pw32) ----
__global__ __launch_bounds__(256) void k_prep(
    const float* __restrict__ w1, const float* __restrict__ w2,
    const float* __restrict__ cb, float* __restrict__ w1t,
    float* __restrict__ w2t, float* __restrict__ bnG) {
  int t = threadIdx.x;
  for (int i = t; i < 8192; i += 256) {
    int tap = i >> 5, co = i & 31;
    w2t[i] = w2[co * 256 + tap];
  }
  for (int i = t; i < 768; i += 256) {
    int tap = i >> 4, co = i & 15;            // tap = ci*16 + r*4 + c
    w1t[i] = w1[co * 48 + tap];
  }
  for (int k = t; k < 512; k += 256) {
    float p[32];
    #pragma unroll
    for (int d = 0; d < 32; d++) { float c = cb[k * 32 + d]; p[d] = c * c; }
    bnG[k] = pw32(p);
  }
}

// ---- conv1: thread = pixel, acc[16] over co; f32 FMA taps (ci,r,c) ----
// Per tap: 1 image load + 16 FMAs with wave-uniform w1t scalar loads.
__global__ __launch_bounds__(256) void k_conv1(
    const float* __restrict__ img, const float* __restrict__ w1t,
    const float* __restrict__ b1, float* __restrict__ h1, int b0) {
  int idx = blockIdx.x * 256 + threadIdx.x;   // bl*16384 + y*128 + x
  int x  = idx & 127;
  int y  = (idx >> 7) & 127;                  // wave-uniform (128 = 2 waves)
  int bl = idx >> 14;
  const float* im = img + (long)(b0 + bl) * 196608;
  float acc[16];
  #pragma unroll
  for (int q = 0; q < 16; q++) acc[q] = 0.f;
  int iy0 = 2 * y - 1, ix0 = 2 * x - 1;
  for (int ci = 0; ci < 3; ci++) {
    const float* imc = im + ci * 65536;
    for (int r = 0; r < 4; r++) {
      int iy = iy0 + r;
      if ((unsigned)iy >= 256u) continue;     // wave-uniform skip (zero row)
      const float* row = imc + iy * 256;
      for (int c = 0; c < 4; c++) {
        int ix = ix0 + c;
        float hv = ((unsigned)ix < 256u) ? row[ix] : 0.f;  // fmaf(0,w,a)==a
        const float* wp = w1t + ((ci * 16 + r * 4 + c) << 4);  // uniform
        #pragma unroll
        for (int co = 0; co < 16; co++)
          acc[co] = fmaf(hv, wp[co], acc[co]);
      }
    }
  }
  long hbase = (long)bl * 262144 + y * 128 + x;
  #pragma unroll
  for (int co = 0; co < 16; co++)             // bias post-add, relu
    h1[hbase + (long)co * 16384] = fmaxf(acc[co] + b1[co], 0.f);
}

// ---- conv2 (f32 FMA) + relu -> z NHWC (enct scratch) ----
// No LDS: w2t / b2 wave-uniform -> scalar loads.
__global__ __launch_bounds__(256, 3) void k_conv2z(
    const float* __restrict__ h1, const float* __restrict__ w2t,
    const float* __restrict__ b2, float* __restrict__ enct, int b0) {
  int t = threadIdx.x;
  int ppix = blockIdx.x * 256 + t;  // bl*4096 + y*64 + x
  int x  = ppix & 63;
  int y  = (ppix >> 6) & 63;
  int bl = ppix >> 12;
  int bg = b0 + bl;

  float z[32];
  #pragma unroll
  for (int q = 0; q < 32; q++) z[q] = 0.f;

  // taps (ci,r,c) ascending, f32 FMA per output channel (order == baseline)
  int iy0 = 2 * y - 1, ix0 = 2 * x - 1;
  for (int ci = 0; ci < 16; ci++) {
    long hbase = (long)bl * 262144 + (long)ci * 16384;
    for (int r = 0; r < 4; r++) {
      int iy = iy0 + r;
      if ((unsigned)iy >= 128u) continue;     // wave-uniform
      const float* hrow = h1 + hbase + (long)iy * 128;
      const float* wrow = w2t + ((ci * 16 + r * 4) << 5);
      for (int c = 0; c < 4; c++) {
        int ix = ix0 + c;
        float hv = ((unsigned)ix < 128u) ? hrow[ix] : 0.f;
        const float* wp = wrow + (c << 5);     // uniform -> s_load_dwordx16 x2
        #pragma unroll
        for (int co = 0; co < 32; co++)
          z[co] = fmaf(hv, wp[co], z[co]);
      }
    }
  }
  float4* et4 = (float4*)(enct + ((long)bg * 4096 + y * 64 + x) * 32);
  #pragma unroll
  for (int d4 = 0; d4 < 8; d4++) {
    float4 v;
    v.x = fmaxf(z[d4 * 4 + 0] + b2[d4 * 4 + 0], 0.f);
    v.y = fmaxf(z[d4 * 4 + 1] + b2[d4 * 4 + 1], 0.f);
    v.z = fmaxf(z[d4 * 4 + 2] + b2[d4 * 4 + 2], 0.f);
    v.w = fmaxf(z[d4 * 4 + 3] + b2[d4 * 4 + 3], 0.f);
    et4[d4] = v;
  }
}

// ---- vq epilogue for channel block W (compile-time -> z stays in regs) ----
template <int W>
__device__ __forceinline__ double vq_epi(const float* cw, const float (&z)[32],
                                         float* __restrict__ enc, long ebase,
                                         float4* et4) {
  double ls = 0.0;
  #pragma unroll
  for (int i4 = 0; i4 < 2; i4++) {
    int d = W * 8 + i4 * 4;
    float f0 = cw[d + 0] - z[d + 0], e0 = z[d + 0] + f0;
    float f1 = cw[d + 1] - z[d + 1], e1 = z[d + 1] + f1;
    float f2 = cw[d + 2] - z[d + 2], e2 = z[d + 2] + f2;
    float f3 = cw[d + 3] - z[d + 3], e3 = z[d + 3] + f3;
    enc[ebase + (long)(d + 0) * 4096] = e0;
    enc[ebase + (long)(d + 1) * 4096] = e1;
    enc[ebase + (long)(d + 2) * 4096] = e2;
    enc[ebase + (long)(d + 3) * 4096] = e3;
    ls += (double)f0 * (double)f0;
    ls += (double)f1 * (double)f1;
    ls += (double)f2 * (double)f2;
    ls += (double)f3 * (double)f3;
    float4 v; v.x = e0; v.y = e1; v.z = e2; v.w = e3;
    et4[W * 2 + i4] = v;                      // in-place final enc_t
  }
  return ls;
}

// ---- vq: block = 4 waves x 64 pixels (one (bl,y) row). Wave w scans codes
// [w*128,(w+1)*128). w is pushed through readfirstlane -> SGPR, so k and all
// cb/bnG addresses are compiler-UNIFORM -> s_load_dwordx16 (the R11 regress
// was divergence analysis treating t>>6 as divergent -> VMEM broadcasts).
// Per-wave argmin -> LDS -> ascending-w strict-< combine == np first-index.
__global__ __launch_bounds__(256) void k_vq(
    const float* __restrict__ cb, const float* __restrict__ bnG,
    float* __restrict__ enc, float* enct,
    double* __restrict__ partial, int b0) {
  __shared__ float sb[256];
  __shared__ int   sq[256];
  __shared__ double sls[4];
  int t = threadIdx.x, l = t & 63;
  int w = __builtin_amdgcn_readfirstlane(t >> 6);  // SGPR: uniform by constr.
  int yy = blockIdx.x & 63;                   // blockIdx.x = bl*64 + y
  int bl = blockIdx.x >> 6;
  int bg = b0 + bl;
  long pg = (long)bg * 4096 + yy * 64 + l;    // global pixel (x = lane)

  float z[32];
  const float4* z4 = (const float4*)(enct + pg * 32);
  #pragma unroll
  for (int i = 0; i < 8; i++) {
    float4 v = z4[i];
    z[i * 4 + 0] = v.x; z[i * 4 + 1] = v.y;
    z[i * 4 + 2] = v.z; z[i * 4 + 3] = v.w;
  }
  // a = ||z||^2 via np pairwise-32 of f32 products (redundant per wave, same)
  float pz[32];
  #pragma unroll
  for (int d = 0; d < 32; d++) pz[d] = z[d] * z[d];
  float a = pw32(pz);

  // dist_k = (a + b_k) - 2*m_k, all f32; m_k = sequential FMA dot.
  // 4 k's in flight; per-chain FMA order unchanged; ascending k, strict <.
  int kbase = w << 7;                         // SGPR-uniform
  float best = FLT_MAX; int bq = kbase;
  for (int k = kbase; k < kbase + 128; k += 4) {
    const float* c0 = cb + (k << 5);          // uniform -> scalar loads
    float m0 = 0.f, m1 = 0.f, m2 = 0.f, m3 = 0.f;
    #pragma unroll
    for (int d = 0; d < 32; d++) {
      m0 = fmaf(z[d], c0[d],      m0);
      m1 = fmaf(z[d], c0[32 + d], m1);
      m2 = fmaf(z[d], c0[64 + d], m2);
      m3 = fmaf(z[d], c0[96 + d], m3);
    }
    float d0 = (a + bnG[k])     - 2.0f * m0;
    float d1 = (a + bnG[k + 1]) - 2.0f * m1;
    float d2 = (a + bnG[k + 2]) - 2.0f * m2;
    float d3 = (a + bnG[k + 3]) - 2.0f * m3;
    if (d0 < best) { best = d0; bq = k; }
    if (d1 < best) { best = d1; bq = k + 1; }
    if (d2 < best) { best = d2; bq = k + 2; }
    if (d3 < best) { best = d3; bq = k + 3; }
  }
  sb[t] = best; sq[t] = bq;
  __syncthreads();
  float gb = sb[l]; int gq = sq[l];
  #pragma unroll
  for (int ww = 1; ww < 4; ww++) {            // ascending k-quarters; ties ->
    float ob = sb[(ww << 6) + l];             // keep lower w (lower k) == np
    int   oq = sq[(ww << 6) + l];
    if (ob < gb) { gb = ob; gq = oq; }
  }

  const float* cw = cb + (gq << 5);           // per-lane gather (L2-hot)
  long ebase = (long)bg * 131072 + yy * 64 + l;
  float4* et4 = (float4*)(enct + pg * 32);
  double ls;
  if      (w == 0) ls = vq_epi<0>(cw, z, enc, ebase, et4);
  else if (w == 1) ls = vq_epi<1>(cw, z, enc, ebase, et4);
  else if (w == 2) ls = vq_epi<2>(cw, z, enc, ebase, et4);
  else             ls = vq_epi<3>(cw, z, enc, ebase, et4);

  #pragma unroll
  for (int off = 32; off > 0; off >>= 1)
    ls += __shfl_down(ls, off, 64);
  if (l == 0) sls[w] = ls;
  __syncthreads();
  if (t == 0)
    partial[(long)b0 * 64 + blockIdx.x] = ((sls[0] + sls[1]) + sls[2]) + sls[3];
}

// ---- deconv1: ConvT(32->16,k4,s2,p1)+relu ----
// Thread = output pixel, acc[16] over all co (16 independent FMA chains).
// Reads enc_t NHWC (float4), writes d1_t NHWC (contiguous 64B per lane).
__global__ __launch_bounds__(256) void k_deconv1(
    const float* __restrict__ enct, const float* __restrict__ dw1,
    const float* __restrict__ db1, float* __restrict__ d1t, int b0) {
  __shared__ float w[8192];
  for (int i = threadIdx.x; i < 8192; i += 256) {
    int co = i & 15, ci = (i >> 4) & 31, kk = i >> 9;
    w[i] = dw1[ci * 256 + co * 16 + kk];
  }
  __syncthreads();
  int idx = blockIdx.x * 256 + threadIdx.x;   // bl*16384 + oy*128 + ox
  int ox = idx & 127;
  int oy = (idx >> 7) & 127;
  int bl = idx >> 14;
  int bg = b0 + bl;
  float acc[16];
  #pragma unroll
  for (int q = 0; q < 16; q++) acc[q] = 0.f;
  int iyt = (oy + 1) >> 1, ixt = (ox + 1) >> 1;
  for (int sy = 0; sy < 2; sy++) {
    int iy = iyt - sy;
    int ky = oy + 1 - 2 * iy;                 // wave-uniform
    if ((unsigned)iy >= 64u || (unsigned)ky >= 4u) continue;
    for (int sx = 0; sx < 2; sx++) {
      int ix = ixt - sx;
      int kx = ox + 1 - 2 * ix;               // per-lane (parity)
      if ((unsigned)ix >= 64u || (unsigned)kx >= 4u) continue;
      const float4* ep4 =
          (const float4*)(enct + ((long)bg * 4096 + iy * 64 + ix) * 32);
      const float4* wl4 = (const float4*)(w + ((ky * 4 + kx) << 9));
      #pragma unroll
      for (int c4 = 0; c4 < 8; c4++) {
        float4 e = ep4[c4];
        #pragma unroll
        for (int j = 0; j < 4; j++) {
          float ev = (j == 0) ? e.x : (j == 1) ? e.y : (j == 2) ? e.z : e.w;
          int ci = c4 * 4 + j;
          #pragma unroll
          for (int q = 0; q < 4; q++) {
            float4 wv = wl4[ci * 4 + q];
            acc[q * 4 + 0] = fmaf(ev, wv.x, acc[q * 4 + 0]);
            acc[q * 4 + 1] = fmaf(ev, wv.y, acc[q * 4 + 1]);
            acc[q * 4 + 2] = fmaf(ev, wv.z, acc[q * 4 + 2]);
            acc[q * 4 + 3] = fmaf(ev, wv.w, acc[q * 4 + 3]);
          }
        }
      }
    }
  }
  float4* o4 = (float4*)(d1t + (long)idx * 16);
  #pragma unroll
  for (int q = 0; q < 4; q++) {
    float4 v;
    v.x = fmaxf(acc[q * 4 + 0] + db1[q * 4 + 0], 0.f);
    v.y = fmaxf(acc[q * 4 + 1] + db1[q * 4 + 1], 0.f);
    v.z = fmaxf(acc[q * 4 + 2] + db1[q * 4 + 2], 0.f);
    v.w = fmaxf(acc[q * 4 + 3] + db1[q * 4 + 3], 0.f);
    o4[q] = v;
  }
}

// ---- deconv2: ConvT(16->3,k4,s2,p1)+relu -> dec f32 ----
// Thread = output pixel, acc[3] over co: d1t float4s loaded ONCE per combo,
// the co loop reuses them from registers (was 3x redundant global reads).
// Weights LDS [co=3][kk=16][ci=16] (ci contiguous), as before.
__global__ __launch_bounds__(256) void k_deconv2(
    const float* __restrict__ d1t, const float* __restrict__ dw2,
    const float* __restrict__ db2, float* __restrict__ dec, int b0) {
  __shared__ float w[768];
  for (int i = threadIdx.x; i < 768; i += 256) {
    int ci = i & 15, kk = (i >> 4) & 15, co = i >> 8;
    w[i] = dw2[ci * 48 + co * 16 + kk];
  }
  __syncthreads();
  int idx = blockIdx.x * 256 + threadIdx.x;  // bl*65536 + oy*256 + ox
  int ox = idx & 255;
  int oy = (idx >> 8) & 255;
  int bl = idx >> 16;
  int bg = b0 + bl;
  float acc[3] = {0.f, 0.f, 0.f};
  int iyt = (oy + 1) >> 1, ixt = (ox + 1) >> 1;
  for (int sy = 0; sy < 2; sy++) {
    int iy = iyt - sy;
    int ky = oy + 1 - 2 * iy;                 // wave-uniform
    if ((unsigned)iy >= 128u || (unsigned)ky >= 4u) continue;
    for (int sx = 0; sx < 2; sx++) {
      int ix = ixt - sx;
      int kx = ox + 1 - 2 * ix;               // per-lane (parity)
      if ((unsigned)ix >= 128u || (unsigned)kx >= 4u) continue;
      const float4* dp4 =
          (const float4*)(d1t + ((long)bl * 16384 + iy * 128 + ix) * 16);
      float4 dv0 = dp4[0], dv1 = dp4[1], dv2 = dp4[2], dv3 = dp4[3];
      int kk4 = (ky * 4 + kx) << 4;
      #pragma unroll
      for (int co = 0; co < 3; co++) {        // per-co chain: ci ascending
        const float4* wp4 = (const float4*)(w + (co << 8) + kk4);
        float4 w0 = wp4[0], w1 = wp4[1], w2 = wp4[2], w3 = wp4[3];
        float a = acc[co];
        a = fmaf(dv0.x, w0.x, a); a = fmaf(dv0.y, w0.y, a);
        a = fmaf(dv0.z, w0.z, a); a = fmaf(dv0.w, w0.w, a);
        a = fmaf(dv1.x, w1.x, a); a = fmaf(dv1.y, w1.y, a);
        a = fmaf(dv1.z, w1.z, a); a = fmaf(dv1.w, w1.w, a);
        a = fmaf(dv2.x, w2.x, a); a = fmaf(dv2.y, w2.y, a);
        a = fmaf(dv2.z, w2.z, a); a = fmaf(dv2.w, w2.w, a);
        a = fmaf(dv3.x, w3.x, a); a = fmaf(dv3.y, w3.y, a);
        a = fmaf(dv3.z, w3.z, a); a = fmaf(dv3.w, w3.w, a);
        acc[co] = a;
      }
    }
  }
  long obase = (long)bg * 196608 + oy * 256 + ox;
  #pragma unroll
  for (int co = 0; co < 3; co++)
    dec[obase + (long)co * 65536] = fmaxf(acc[co] + db2[co], 0.f);
}

__global__ __launch_bounds__(256) void k_loss(
    const double* __restrict__ partial, float* __restrict__ out) {
  __shared__ double r[256];
  int t = threadIdx.x;
  double s = 0.0;
  for (int i = t; i < 2048; i += 256) s += partial[i];
  r[t] = s;
  __syncthreads();
  for (int st = 128; st > 0; st >>= 1) {
    if (t < st) r[t] += r[t + st];
    __syncthreads();
  }
  if (t == 0) out[0] = (float)(2.0 * r[0] / 4194304.0);
}

extern "C" void kernel_launch(void* const* d_in, const int* in_sizes, int n_in,
                              void* d_out, int out_size, void* d_ws, size_t ws_size,
                              hipStream_t stream) {
  const float* imgs = (const float*)d_in[0];
  const float* w1   = (const float*)d_in[1];
  const float* b1   = (const float*)d_in[2];
  const float* w2   = (const float*)d_in[3];
  const float* b2   = (const float*)d_in[4];
  const float* cb   = (const float*)d_in[5];
  const float* dw1  = (const float*)d_in[6];
  const float* db1  = (const float*)d_in[7];
  const float* dw2  = (const float*)d_in[8];
  const float* db2  = (const float*)d_in[9];

  float* out = (float*)d_out;
  float* enc = out;               // (32,32,64,64)  f32
  float* dec = out + 4194304;     // (32,3,256,256) f32
  float* vql = out + 10485760;    // scalar         f32
  // enc_t (NHWC scratch, 16 MB) lives at the TAIL of the dec region; for
  // chunk m, dec written so far = m*cc*196608 floats <= 2097152 +
  // m*cc*131072 (enc_t still needed) since m*cc < 32. Stream-serialized.
  float* enct = dec + 2097152;

  // ws carve (top): partial(16K) | bnG(2K) | w2t(32K) | w1t(3K) | h1/d1t below
  long ws = (long)ws_size;
  long top = (ws - 16384) & ~255L;
  double* partial = (double*)((char*)d_ws + top);
  top = (top - 2048) & ~255L;
  float* bnG = (float*)((char*)d_ws + top);
  top = (top - 32768) & ~255L;
  float* w2t = (float*)((char*)d_ws + top);
  top = (top - 3072) & ~255L;
  float* w1t = (float*)((char*)d_ws + top);

  k_prep<<<1, 256, 0, stream>>>(w1, w2, cb, w1t, w2t, bnG);

  // h1 (encode) and d1_t (decode) alias: each cc MiB, chunked through ws
  int cc = 1;
  for (int c = 32; c >= 1; c >>= 1)
    if ((long)c * 1048576 <= top) { cc = c; break; }

  float* h1 = (float*)d_ws;
  for (int b0 = 0; b0 < 32; b0 += cc) {
    k_conv1<<<cc * 64, 256, 0, stream>>>(imgs, w1t, b1, h1, b0);
    k_conv2z<<<cc * 16, 256, 0, stream>>>(h1, w2t, b2, enct, b0);
    k_vq<<<cc * 64, 256, 0, stream>>>(cb, bnG, enc, enct, partial, b0);
  }

  float* d1t = (float*)d_ws;
  for (int b0 = 0; b0 < 32; b0 += cc) {
    k_deconv1<<<cc * 64, 256, 0, stream>>>(enct, dw1, db1, d1t, b0);
    k_deconv2<<<cc * 256, 256, 0, stream>>>(d1t, dw2, db2, dec, b0);
  }

  k_loss<<<1, 256, 0, stream>>>(partial, vql);
}

// Round 9
// 352.983 us; speedup vs baseline: 2.1442x; 1.0925x over previous
//
#include <hip/hip_runtime.h>
#include <float.h>

// VQVAE forward, MI355X. Inputs f32, output buffer f32, order [encoded |
// decoded | vq_loss]; harness compares after bf16-rounding both sides.
// KEY (R7 forensics): the np reference computes the VQ distances in FLOAT32
// including the shared ||z||^2 (~0.9) term -> near-ties quantize equal in
// f32 (ULP ~6e-8) and np.argmin tie-breaks FIRST-INDEX. This version
// emulates the np f32 pipeline bit-for-bit: f32 FMA convs (im2col tap order
// ci,ky,kx; bias post-add), numpy pairwise-32 sums, sequential-FMA dot,
// dist=(a+b_k)-2*m_k in f32, first-index argmin, enc = z + (z_q - z) in f32.
//
// R8: conv2vq de-LDS'd (wave-uniform operands -> scalar loads). R9: NHWC
// intermediates for the deconvs. R10-R12: conv2z + k_vq split (wave index
// through readfirstlane to keep the codebook scan scalar). R13: conv1
// thread=pixel/acc[16]. R14/R15: deconv2 thread=pixel/acc[3] (was 3x
// redundant d1t reads) -> 385us total, k_vq now top at 94us (floor 27us).
// R16 (this round): k_vq occupancy was 42% (~3.4 waves/SIMD vs SGPR cap 7)
// and each block's 4 waves streamed 4 different 16KB codebook quarters
// through the shared scalar cache. Now 8 waves/block (512 thr), wave w
// scans a 64-code slice; per-thread FMA halves; resident waves ~2x; wave
// epilogue = 4 channels each. Combine ascending-w strict-< == np
// first-index. k_conv2z was grid-limited (512 blocks = 2/CU): co-split
// into 2 blocks/tile (co 0-15 / 16-31); per-co FMA chains independent and
// unchanged -> bit-exact; w2t reads stay uniform s_load_dwordx16.
#pragma clang fp contract(off)
// (explicit fmaf() still emits hardware FMA; everything else stays per-op IEEE)

// numpy pairwise_sum for n=32: r[j]=a[j]; r[j]+=a[8+j]; +=a[16+j]; +=a[24+j];
// result = ((r0+r1)+(r2+r3))+((r4+r5)+(r6+r7))
__device__ __forceinline__ float pw32(const float* p) {
  float r0 = p[0], r1 = p[1], r2 = p[2], r3 = p[3];
  float r4 = p[4], r5 = p[5], r6 = p[6], r7 = p[7];
  r0 += p[8];  r1 += p[9];  r2 += p[10]; r3 += p[11];
  r4 += p[12]; r5 += p[13]; r6 += p[14]; r7 += p[15];
  r0 += p[16]; r1 += p[17]; r2 += p[18]; r3 += p[19];
  r4 += p[20]; r5 += p[21]; r6 += p[22]; r7 += p[23];
  r0 += p[24]; r1 += p[25]; r2 += p[26]; r3 += p[27];
  r4 += p[28]; r5 += p[29]; r6 += p[30]; r7 += p[31];
  return ((r0 + r1) + (r2 + r3)) + ((r4 + r5) + (r6 + r7));
}

// ---- prep: w2t[tap*32+co]=w2[co*256+tap]; w1t[tap*16+co]=w1[co*48+tap];
//      bnG[k] = ||c_k||^2 (np pw32) ----
__global__ __launch_bounds__(256) void k_prep(
    const float* __restrict__ w1, const float* __restrict__ w2,
    const float* __restrict__ cb, float* __restrict__ w1t,
    float* __restrict__ w2t, float* __restrict__ bnG) {
  int t = threadIdx.x;
  for (int i = t; i < 8192; i += 256) {
    int tap = i >> 5, co = i & 31;
    w2t[i] = w2[co * 256 + tap];
  }
  for (int i = t; i < 768; i += 256) {
    int tap = i >> 4, co = i & 15;            // tap = ci*16 + r*4 + c
    w1t[i] = w1[co * 48 + tap];
  }
  for (int k = t; k < 512; k += 256) {
    float p[32];
    #pragma unroll
    for (int d = 0; d < 32; d++) { float c = cb[k * 32 + d]; p[d] = c * c; }
    bnG[k] = pw32(p);
  }
}

// ---- conv1: thread = pixel, acc[16] over co; f32 FMA taps (ci,r,c) ----
// Per tap: 1 image load + 16 FMAs with wave-uniform w1t scalar loads.
__global__ __launch_bounds__(256) void k_conv1(
    const float* __restrict__ img, const float* __restrict__ w1t,
    const float* __restrict__ b1, float* __restrict__ h1, int b0) {
  int idx = blockIdx.x * 256 + threadIdx.x;   // bl*16384 + y*128 + x
  int x  = idx & 127;
  int y  = (idx >> 7) & 127;                  // wave-uniform (128 = 2 waves)
  int bl = idx >> 14;
  const float* im = img + (long)(b0 + bl) * 196608;
  float acc[16];
  #pragma unroll
  for (int q = 0; q < 16; q++) acc[q] = 0.f;
  int iy0 = 2 * y - 1, ix0 = 2 * x - 1;
  for (int ci = 0; ci < 3; ci++) {
    const float* imc = im + ci * 65536;
    for (int r = 0; r < 4; r++) {
      int iy = iy0 + r;
      if ((unsigned)iy >= 256u) continue;     // wave-uniform skip (zero row)
      const float* row = imc + iy * 256;
      for (int c = 0; c < 4; c++) {
        int ix = ix0 + c;
        float hv = ((unsigned)ix < 256u) ? row[ix] : 0.f;  // fmaf(0,w,a)==a
        const float* wp = w1t + ((ci * 16 + r * 4 + c) << 4);  // uniform
        #pragma unroll
        for (int co = 0; co < 16; co++)
          acc[co] = fmaf(hv, wp[co], acc[co]);
      }
    }
  }
  long hbase = (long)bl * 262144 + y * 128 + x;
  #pragma unroll
  for (int co = 0; co < 16; co++)             // bias post-add, relu
    h1[hbase + (long)co * 16384] = fmaxf(acc[co] + b1[co], 0.f);
}

// ---- conv2 (f32 FMA) + relu -> z NHWC (enct scratch), co-split 2-way ----
// blockIdx.x = tile*2 + half; half h computes co in [16h, 16h+16). Per-co
// FMA chain (taps ci,r,c ascending) identical to the unsplit version.
// No LDS: w2t / b2 wave-uniform -> scalar loads (dwordx16 at offset 16h).
__global__ __launch_bounds__(256, 3) void k_conv2z(
    const float* __restrict__ h1, const float* __restrict__ w2t,
    const float* __restrict__ b2, float* __restrict__ enct, int b0) {
  int t = threadIdx.x;
  int half = blockIdx.x & 1;
  int coff = half << 4;                       // 0 or 16 (block-uniform)
  int ppix = (blockIdx.x >> 1) * 256 + t;     // bl*4096 + y*64 + x
  int x  = ppix & 63;
  int y  = (ppix >> 6) & 63;
  int bl = ppix >> 12;
  int bg = b0 + bl;

  float z[16];
  #pragma unroll
  for (int q = 0; q < 16; q++) z[q] = 0.f;

  // taps (ci,r,c) ascending, f32 FMA per output channel (order == baseline)
  int iy0 = 2 * y - 1, ix0 = 2 * x - 1;
  for (int ci = 0; ci < 16; ci++) {
    long hbase = (long)bl * 262144 + (long)ci * 16384;
    for (int r = 0; r < 4; r++) {
      int iy = iy0 + r;
      if ((unsigned)iy >= 128u) continue;     // wave-uniform
      const float* hrow = h1 + hbase + (long)iy * 128;
      const float* wrow = w2t + ((ci * 16 + r * 4) << 5) + coff;
      for (int c = 0; c < 4; c++) {
        int ix = ix0 + c;
        float hv = ((unsigned)ix < 128u) ? hrow[ix] : 0.f;
        const float* wp = wrow + (c << 5);     // uniform -> s_load_dwordx16
        #pragma unroll
        for (int co = 0; co < 16; co++)
          z[co] = fmaf(hv, wp[co], z[co]);
      }
    }
  }
  float4* et4 = (float4*)(enct + ((long)bg * 4096 + y * 64 + x) * 32 + coff);
  #pragma unroll
  for (int d4 = 0; d4 < 4; d4++) {
    float4 v;
    v.x = fmaxf(z[d4 * 4 + 0] + b2[coff + d4 * 4 + 0], 0.f);
    v.y = fmaxf(z[d4 * 4 + 1] + b2[coff + d4 * 4 + 1], 0.f);
    v.z = fmaxf(z[d4 * 4 + 2] + b2[coff + d4 * 4 + 2], 0.f);
    v.w = fmaxf(z[d4 * 4 + 3] + b2[coff + d4 * 4 + 3], 0.f);
    et4[d4] = v;
  }
}

// ---- vq epilogue for channel block W (4 channels; compile-time W) ----
template <int W>
__device__ __forceinline__ double vq_epi(const float* cw, const float (&z)[32],
                                         float* __restrict__ enc, long ebase,
                                         float4* et4) {
  int d = W * 4;
  float f0 = cw[d + 0] - z[d + 0], e0 = z[d + 0] + f0;
  float f1 = cw[d + 1] - z[d + 1], e1 = z[d + 1] + f1;
  float f2 = cw[d + 2] - z[d + 2], e2 = z[d + 2] + f2;
  float f3 = cw[d + 3] - z[d + 3], e3 = z[d + 3] + f3;
  enc[ebase + (long)(d + 0) * 4096] = e0;
  enc[ebase + (long)(d + 1) * 4096] = e1;
  enc[ebase + (long)(d + 2) * 4096] = e2;
  enc[ebase + (long)(d + 3) * 4096] = e3;
  double ls = 0.0;
  ls += (double)f0 * (double)f0;
  ls += (double)f1 * (double)f1;
  ls += (double)f2 * (double)f2;
  ls += (double)f3 * (double)f3;
  float4 v; v.x = e0; v.y = e1; v.z = e2; v.w = e3;
  et4[W] = v;                                 // in-place final enc_t
  return ls;
}

// ---- vq: block = 8 waves x 64 pixels (one (bl,y) row). Wave w scans codes
// [w*64,(w+1)*64). w through readfirstlane -> SGPR-uniform -> cb/bnG stay
// s_load_dwordx16 (R11 lesson). Per-wave argmin -> LDS -> ascending-w
// strict-< combine == np first-index. All z-reads happen before the first
// barrier; in-place enct rewrite happens after the second -> race-free.
__global__ __launch_bounds__(512) void k_vq(
    const float* __restrict__ cb, const float* __restrict__ bnG,
    float* __restrict__ enc, float* enct,
    double* __restrict__ partial, int b0) {
  __shared__ float sb[512];
  __shared__ int   sq[512];
  __shared__ double sls[8];
  int t = threadIdx.x, l = t & 63;
  int w = __builtin_amdgcn_readfirstlane(t >> 6);  // 0..7, SGPR-uniform
  int yy = blockIdx.x & 63;                   // blockIdx.x = bl*64 + y
  int bl = blockIdx.x >> 6;
  int bg = b0 + bl;
  long pg = (long)bg * 4096 + yy * 64 + l;    // global pixel (x = lane)

  float z[32];
  const float4* z4 = (const float4*)(enct + pg * 32);
  #pragma unroll
  for (int i = 0; i < 8; i++) {
    float4 v = z4[i];
    z[i * 4 + 0] = v.x; z[i * 4 + 1] = v.y;
    z[i * 4 + 2] = v.z; z[i * 4 + 3] = v.w;
  }
  // a = ||z||^2 via np pairwise-32 of f32 products (redundant per wave, same)
  float pz[32];
  #pragma unroll
  for (int d = 0; d < 32; d++) pz[d] = z[d] * z[d];
  float a = pw32(pz);

  // dist_k = (a + b_k) - 2*m_k, all f32; m_k = sequential FMA dot.
  // 4 k's in flight; per-chain FMA order unchanged; ascending k, strict <.
  int kbase = w << 6;                         // SGPR-uniform 64-code slice
  float best = FLT_MAX; int bq = kbase;
  for (int k = kbase; k < kbase + 64; k += 4) {
    const float* c0 = cb + (k << 5);          // uniform -> scalar loads
    float m0 = 0.f, m1 = 0.f, m2 = 0.f, m3 = 0.f;
    #pragma unroll
    for (int d = 0; d < 32; d++) {
      m0 = fmaf(z[d], c0[d],      m0);
      m1 = fmaf(z[d], c0[32 + d], m1);
      m2 = fmaf(z[d], c0[64 + d], m2);
      m3 = fmaf(z[d], c0[96 + d], m3);
    }
    float d0 = (a + bnG[k])     - 2.0f * m0;
    float d1 = (a + bnG[k + 1]) - 2.0f * m1;
    float d2 = (a + bnG[k + 2]) - 2.0f * m2;
    float d3 = (a + bnG[k + 3]) - 2.0f * m3;
    if (d0 < best) { best = d0; bq = k; }
    if (d1 < best) { best = d1; bq = k + 1; }
    if (d2 < best) { best = d2; bq = k + 2; }
    if (d3 < best) { best = d3; bq = k + 3; }
  }
  sb[t] = best; sq[t] = bq;
  __syncthreads();
  float gb = sb[l]; int gq = sq[l];
  #pragma unroll
  for (int ww = 1; ww < 8; ww++) {            // ascending k-slices; ties ->
    float ob = sb[(ww << 6) + l];             // keep lower w (lower k) == np
    int   oq = sq[(ww << 6) + l];
    if (ob < gb) { gb = ob; gq = oq; }
  }

  const float* cw = cb + (gq << 5);           // per-lane gather (L2-hot)
  long ebase = (long)bg * 131072 + yy * 64 + l;
  float4* et4 = (float4*)(enct + pg * 32);
  double ls;
  if      (w == 0) ls = vq_epi<0>(cw, z, enc, ebase, et4);
  else if (w == 1) ls = vq_epi<1>(cw, z, enc, ebase, et4);
  else if (w == 2) ls = vq_epi<2>(cw, z, enc, ebase, et4);
  else if (w == 3) ls = vq_epi<3>(cw, z, enc, ebase, et4);
  else if (w == 4) ls = vq_epi<4>(cw, z, enc, ebase, et4);
  else if (w == 5) ls = vq_epi<5>(cw, z, enc, ebase, et4);
  else if (w == 6) ls = vq_epi<6>(cw, z, enc, ebase, et4);
  else             ls = vq_epi<7>(cw, z, enc, ebase, et4);

  #pragma unroll
  for (int off = 32; off > 0; off >>= 1)
    ls += __shfl_down(ls, off, 64);
  if (l == 0) sls[w] = ls;
  __syncthreads();
  if (t == 0) {
    double s = sls[0];
    #pragma unroll
    for (int ww = 1; ww < 8; ww++) s += sls[ww];
    partial[(long)b0 * 64 + blockIdx.x] = s;
  }
}

// ---- deconv1: ConvT(32->16,k4,s2,p1)+relu ----
// Thread = output pixel, acc[16] over all co (16 independent FMA chains).
// Reads enc_t NHWC (float4), writes d1_t NHWC (contiguous 64B per lane).
__global__ __launch_bounds__(256) void k_deconv1(
    const float* __restrict__ enct, const float* __restrict__ dw1,
    const float* __restrict__ db1, float* __restrict__ d1t, int b0) {
  __shared__ float w[8192];
  for (int i = threadIdx.x; i < 8192; i += 256) {
    int co = i & 15, ci = (i >> 4) & 31, kk = i >> 9;
    w[i] = dw1[ci * 256 + co * 16 + kk];
  }
  __syncthreads();
  int idx = blockIdx.x * 256 + threadIdx.x;   // bl*16384 + oy*128 + ox
  int ox = idx & 127;
  int oy = (idx >> 7) & 127;
  int bl = idx >> 14;
  int bg = b0 + bl;
  float acc[16];
  #pragma unroll
  for (int q = 0; q < 16; q++) acc[q] = 0.f;
  int iyt = (oy + 1) >> 1, ixt = (ox + 1) >> 1;
  for (int sy = 0; sy < 2; sy++) {
    int iy = iyt - sy;
    int ky = oy + 1 - 2 * iy;                 // wave-uniform
    if ((unsigned)iy >= 64u || (unsigned)ky >= 4u) continue;
    for (int sx = 0; sx < 2; sx++) {
      int ix = ixt - sx;
      int kx = ox + 1 - 2 * ix;               // per-lane (parity)
      if ((unsigned)ix >= 64u || (unsigned)kx >= 4u) continue;
      const float4* ep4 =
          (const float4*)(enct + ((long)bg * 4096 + iy * 64 + ix) * 32);
      const float4* wl4 = (const float4*)(w + ((ky * 4 + kx) << 9));
      #pragma unroll
      for (int c4 = 0; c4 < 8; c4++) {
        float4 e = ep4[c4];
        #pragma unroll
        for (int j = 0; j < 4; j++) {
          float ev = (j == 0) ? e.x : (j == 1) ? e.y : (j == 2) ? e.z : e.w;
          int ci = c4 * 4 + j;
          #pragma unroll
          for (int q = 0; q < 4; q++) {
            float4 wv = wl4[ci * 4 + q];
            acc[q * 4 + 0] = fmaf(ev, wv.x, acc[q * 4 + 0]);
            acc[q * 4 + 1] = fmaf(ev, wv.y, acc[q * 4 + 1]);
            acc[q * 4 + 2] = fmaf(ev, wv.z, acc[q * 4 + 2]);
            acc[q * 4 + 3] = fmaf(ev, wv.w, acc[q * 4 + 3]);
          }
        }
      }
    }
  }
  float4* o4 = (float4*)(d1t + (long)idx * 16);
  #pragma unroll
  for (int q = 0; q < 4; q++) {
    float4 v;
    v.x = fmaxf(acc[q * 4 + 0] + db1[q * 4 + 0], 0.f);
    v.y = fmaxf(acc[q * 4 + 1] + db1[q * 4 + 1], 0.f);
    v.z = fmaxf(acc[q * 4 + 2] + db1[q * 4 + 2], 0.f);
    v.w = fmaxf(acc[q * 4 + 3] + db1[q * 4 + 3], 0.f);
    o4[q] = v;
  }
}

// ---- deconv2: ConvT(16->3,k4,s2,p1)+relu -> dec f32 ----
// Thread = output pixel, acc[3] over co: d1t float4s loaded ONCE per combo,
// the co loop reuses them from registers. Weights LDS [co=3][kk=16][ci=16].
__global__ __launch_bounds__(256) void k_deconv2(
    const float* __restrict__ d1t, const float* __restrict__ dw2,
    const float* __restrict__ db2, float* __restrict__ dec, int b0) {
  __shared__ float w[768];
  for (int i = threadIdx.x; i < 768; i += 256) {
    int ci = i & 15, kk = (i >> 4) & 15, co = i >> 8;
    w[i] = dw2[ci * 48 + co * 16 + kk];
  }
  __syncthreads();
  int idx = blockIdx.x * 256 + threadIdx.x;  // bl*65536 + oy*256 + ox
  int ox = idx & 255;
  int oy = (idx >> 8) & 255;
  int bl = idx >> 16;
  int bg = b0 + bl;
  float acc[3] = {0.f, 0.f, 0.f};
  int iyt = (oy + 1) >> 1, ixt = (ox + 1) >> 1;
  for (int sy = 0; sy < 2; sy++) {
    int iy = iyt - sy;
    int ky = oy + 1 - 2 * iy;                 // wave-uniform
    if ((unsigned)iy >= 128u || (unsigned)ky >= 4u) continue;
    for (int sx = 0; sx < 2; sx++) {
      int ix = ixt - sx;
      int kx = ox + 1 - 2 * ix;               // per-lane (parity)
      if ((unsigned)ix >= 128u || (unsigned)kx >= 4u) continue;
      const float4* dp4 =
          (const float4*)(d1t + ((long)bl * 16384 + iy * 128 + ix) * 16);
      float4 dv0 = dp4[0], dv1 = dp4[1], dv2 = dp4[2], dv3 = dp4[3];
      int kk4 = (ky * 4 + kx) << 4;
      #pragma unroll
      for (int co = 0; co < 3; co++) {        // per-co chain: ci ascending
        const float4* wp4 = (const float4*)(w + (co << 8) + kk4);
        float4 w0 = wp4[0], w1 = wp4[1], w2 = wp4[2], w3 = wp4[3];
        float a = acc[co];
        a = fmaf(dv0.x, w0.x, a); a = fmaf(dv0.y, w0.y, a);
        a = fmaf(dv0.z, w0.z, a); a = fmaf(dv0.w, w0.w, a);
        a = fmaf(dv1.x, w1.x, a); a = fmaf(dv1.y, w1.y, a);
        a = fmaf(dv1.z, w1.z, a); a = fmaf(dv1.w, w1.w, a);
        a = fmaf(dv2.x, w2.x, a); a = fmaf(dv2.y, w2.y, a);
        a = fmaf(dv2.z, w2.z, a); a = fmaf(dv2.w, w2.w, a);
        a = fmaf(dv3.x, w3.x, a); a = fmaf(dv3.y, w3.y, a);
        a = fmaf(dv3.z, w3.z, a); a = fmaf(dv3.w, w3.w, a);
        acc[co] = a;
      }
    }
  }
  long obase = (long)bg * 196608 + oy * 256 + ox;
  #pragma unroll
  for (int co = 0; co < 3; co++)
    dec[obase + (long)co * 65536] = fmaxf(acc[co] + db2[co], 0.f);
}

__global__ __launch_bounds__(256) void k_loss(
    const double* __restrict__ partial, float* __restrict__ out) {
  __shared__ double r[256];
  int t = threadIdx.x;
  double s = 0.0;
  for (int i = t; i < 2048; i += 256) s += partial[i];
  r[t] = s;
  __syncthreads();
  for (int st = 128; st > 0; st >>= 1) {
    if (t < st) r[t] += r[t + st];
    __syncthreads();
  }
  if (t == 0) out[0] = (float)(2.0 * r[0] / 4194304.0);
}

extern "C" void kernel_launch(void* const* d_in, const int* in_sizes, int n_in,
                              void* d_out, int out_size, void* d_ws, size_t ws_size,
                              hipStream_t stream) {
  const float* imgs = (const float*)d_in[0];
  const float* w1   = (const float*)d_in[1];
  const float* b1   = (const float*)d_in[2];
  const float* w2   = (const float*)d_in[3];
  const float* b2   = (const float*)d_in[4];
  const float* cb   = (const float*)d_in[5];
  const float* dw1  = (const float*)d_in[6];
  const float* db1  = (const float*)d_in[7];
  const float* dw2  = (const float*)d_in[8];
  const float* db2  = (const float*)d_in[9];

  float* out = (float*)d_out;
  float* enc = out;               // (32,32,64,64)  f32
  float* dec = out + 4194304;     // (32,3,256,256) f32
  float* vql = out + 10485760;    // scalar         f32
  // enc_t (NHWC scratch, 16 MB) lives at the TAIL of the dec region; for
  // chunk m, dec written so far = m*cc*196608 floats <= 2097152 +
  // m*cc*131072 (enc_t still needed) since m*cc < 32. Stream-serialized.
  float* enct = dec + 2097152;

  // ws carve (top): partial(16K) | bnG(2K) | w2t(32K) | w1t(3K) | h1/d1t below
  long ws = (long)ws_size;
  long top = (ws - 16384) & ~255L;
  double* partial = (double*)((char*)d_ws + top);
  top = (top - 2048) & ~255L;
  float* bnG = (float*)((char*)d_ws + top);
  top = (top - 32768) & ~255L;
  float* w2t = (float*)((char*)d_ws + top);
  top = (top - 3072) & ~255L;
  float* w1t = (float*)((char*)d_ws + top);

  k_prep<<<1, 256, 0, stream>>>(w1, w2, cb, w1t, w2t, bnG);

  // h1 (encode) and d1_t (decode) alias: each cc MiB, chunked through ws
  int cc = 1;
  for (int c = 32; c >= 1; c >>= 1)
    if ((long)c * 1048576 <= top) { cc = c; break; }

  float* h1 = (float*)d_ws;
  for (int b0 = 0; b0 < 32; b0 += cc) {
    k_conv1<<<cc * 64, 256, 0, stream>>>(imgs, w1t, b1, h1, b0);
    k_conv2z<<<cc * 32, 256, 0, stream>>>(h1, w2t, b2, enct, b0);
    k_vq<<<cc * 64, 512, 0, stream>>>(cb, bnG, enc, enct, partial, b0);
  }

  float* d1t = (float*)d_ws;
  for (int b0 = 0; b0 < 32; b0 += cc) {
    k_deconv1<<<cc * 64, 256, 0, stream>>>(enct, dw1, db1, d1t, b0);
    k_deconv2<<<cc * 256, 256, 0, stream>>>(d1t, dw2, db2, dec, b0);
  }

  k_loss<<<1, 256, 0, stream>>>(partial, vql);
}